// Round 1
// baseline (2335.337 us; speedup 1.0000x reference)
//
#include <hip/hip_runtime.h>
#include <hip/hip_bf16.h>

typedef short bf16x8 __attribute__((ext_vector_type(8)));
typedef float f32x4  __attribute__((ext_vector_type(4)));

#define DEVI __device__ __forceinline__

static constexpr int    NSAMP = 16384;
static constexpr int    TDIM  = 480;
static constexpr int    KTOT  = 21504;

// ---- workspace layout (bytes) ----
static constexpr size_t SZ_B   = (size_t)KTOT * 64 * 2;          // 2,752,512
static constexpr size_t O_BFWD = 0;
static constexpr size_t O_BBWD = O_BFWD + SZ_B;
static constexpr size_t O_HPRE = O_BBWD + SZ_B;                  // f32 N*64
static constexpr size_t O_DH   = O_HPRE + (size_t)NSAMP*64*4;    // bf16 N*64
static constexpr size_t O_W1T  = O_DH   + (size_t)NSAMP*64*2;
static constexpr size_t O_W2T  = O_W1T + (size_t)64*64*4;
static constexpr size_t O_W3T  = O_W2T + (size_t)64*64*4;
// total ~11.85 MB

DEVI float b2f(unsigned short s) { union { unsigned u; float f; } v; v.u = (unsigned)s << 16; return v.f; }
DEVI unsigned short f2b(float f) { union { __hip_bfloat16 h; unsigned short s; } v; v.h = __float2bfloat16(f); return v.s; }
DEVI bf16x8 as_bf(uint4 q) { union { uint4 q; bf16x8 v; } u; u.q = q; return u.v; }
DEVI f32x4 mfma16(bf16x8 a, bf16x8 b, f32x4 c) { return __builtin_amdgcn_mfma_f32_16x16x32_bf16(a, b, c, 0, 0, 0); }

// region config: r0 = l0 (128x128), r1 = l1 (64x64, m=3), r2 = l2 (32x32, m=5)
template<int R> struct RC;
template<> struct RC<0> { static constexpr int COLS=128, OFF=0,   STRIDE=136, ROWS=128, NCH=4, NM=1, CBASE=0,   KBASE=0,    OUT=0;   };
template<> struct RC<1> { static constexpr int COLS=192, OFF=128, STRIDE=200, ROWS=64,  NCH=2, NM=3, CBASE=512, KBASE=1024, OUT=128; };
template<> struct RC<2> { static constexpr int COLS=160, OFF=320, STRIDE=168, ROWS=32,  NCH=1, NM=5, CBASE=640, KBASE=1280, OUT=320; };

// ============================================================================
// K0: weight prep.  Bfwd (frag-major for fwd GEMM B-operand), Bbwd (frag-major
// symmetrized, for bwd GEMM A-operand), zero hpre, transpose w1/w2/w3.
// ============================================================================
__global__ __launch_bounds__(256) void k_prep(
    const float* __restrict__ W0, const float* __restrict__ W1, const float* __restrict__ W2,
    const float* __restrict__ w1, const float* __restrict__ w2, const float* __restrict__ w3,
    unsigned short* __restrict__ bfwd, unsigned short* __restrict__ bbwd,
    float* __restrict__ hpre, float* __restrict__ w1t, float* __restrict__ w2t, float* __restrict__ w3t)
{
  const int e = blockIdx.x*256 + threadIdx.x;
  const float CA = 0.0068192924f;   // 1/sqrt(21504)
  const float C1 = 0.0039371205f;   // CA/sqrt(3)
  const float C2 = 0.0030496940f;   // CA/sqrt(5)
  if (e < KTOT*64) {
    { // forward B: frag (chunk=32k x 16h); lane holds B[k=quad*8+j][h=hf*16+col]
      int j = e & 7, lane = (e>>3)&63, hf = (e>>9)&3, chunk = e>>11;
      int k = chunk*32 + (lane>>4)*8 + j;
      int h = hf*16 + (lane&15);
      float v;
      if (k < 16384)      v = CA * W0[(size_t)k*64 + h];
      else if (k < 20480) v = C1 * W1[(size_t)(k-16384)*64 + h];
      else                v = C2 * W2[(size_t)(k-20480)*64 + h];
      bfwd[e] = f2b(v);
    }
    { // backward A: frag (16 k-rows x 32 h); lane holds A[k=kb*16+col][h=kc*32+quad*8+j]
      int j = e & 7, lane = (e>>3)&63, kc = (e>>9)&1, kb = e>>10;
      int k = kb*16 + (lane&15);
      int h = kc*32 + (lane>>4)*8 + j;
      float v;
      if (k < 16384)      { int u=k>>7,    vv=k&127;          v = CA*(W0[(size_t)(u*128+vv)*64+h] + W0[(size_t)(vv*128+u)*64+h]); }
      else if (k < 20480) { int l=k-16384; int u=l>>6, vv=l&63; v = C1*(W1[(size_t)(u*64+vv)*64+h] + W1[(size_t)(vv*64+u)*64+h]); }
      else                { int l=k-20480; int u=l>>5, vv=l&31; v = C2*(W2[(size_t)(u*32+vv)*64+h] + W2[(size_t)(vv*32+u)*64+h]); }
      bbwd[e] = f2b(v);
    }
  }
  if (e < NSAMP*64) hpre[e] = 0.f;
  if (e < 4096) {
    int i = e>>6, j = e&63;
    w1t[j*64+i] = w1[e]; w2t[j*64+i] = w2[e]; w3t[j*64+i] = w3[e];
  }
}

// ---- cooperative x-tile loader: 128 samples x COLS, f32 global -> bf16 LDS ----
template<int R>
DEVI void load_tile(const float* __restrict__ t, int nb, unsigned short* lx)
{
  const int tid = threadIdx.x;
  const int s = tid >> 1, half = tid & 1;
  constexpr int CH = RC<R>::COLS/2;
  const float4* src = reinterpret_cast<const float4*>(t + (size_t)(nb+s)*TDIM + RC<R>::OFF + half*CH);
  unsigned short* dst = lx + s*RC<R>::STRIDE + half*CH;
  #pragma unroll
  for (int e4 = 0; e4 < CH/4; ++e4) {
    float4 v = src[e4];
    ushort4 o; o.x = f2b(v.x); o.y = f2b(v.y); o.z = f2b(v.z); o.w = f2b(v.w);
    *reinterpret_cast<ushort4*>(dst + e4*4) = o;
  }
}

// ============================================================================
// K1: forward TP.  C[n(128/wave), h(64)] += Gram(x) @ Bfwd over this slot's
// k-rows.  A built on the fly: A[n, (u,v)] = sum_m x[n,u,m]*x[n,v,m].
// grid (128 tiles, 4 ksplit) x 256 thr; 16 k-slots per tile; atomicAdd partials.
// ============================================================================
template<int R>
DEVI void fwd_region(const unsigned short* lx, const uint4* __restrict__ bf,
                     int slot, int lane, f32x4 (&acc)[8][4])
{
  constexpr int NM = RC<R>::NM;
  const int quad = lane>>4, col = lane&15;
  for (int u = slot; u < RC<R>::ROWS; u += 16) {
    float xu[8][NM];
    #pragma unroll
    for (int mf = 0; mf < 8; ++mf) {
      const unsigned short* row = lx + (mf*16+col)*RC<R>::STRIDE + u*NM;
      #pragma unroll
      for (int m = 0; m < NM; ++m) xu[mf][m] = b2f(row[m]);
    }
    #pragma unroll
    for (int c = 0; c < RC<R>::NCH; ++c) {
      const int chunk = RC<R>::CBASE + u*RC<R>::NCH + c;
      uint4 bv[4];
      #pragma unroll
      for (int hf = 0; hf < 4; ++hf) bv[hf] = bf[(size_t)(chunk*4 + hf)*64 + lane];
      #pragma unroll
      for (int mf = 0; mf < 8; ++mf) {
        const uint4* xp4 = reinterpret_cast<const uint4*>(
            lx + (mf*16+col)*RC<R>::STRIDE + (c*32 + quad*8)*NM);
        union { unsigned short s[8*NM]; uint4 q[NM]; } xv;
        #pragma unroll
        for (int q = 0; q < NM; ++q) xv.q[q] = xp4[q];
        union { unsigned short s[8]; bf16x8 v; } af;
        #pragma unroll
        for (int j = 0; j < 8; ++j) {
          float p = 0.f;
          #pragma unroll
          for (int m = 0; m < NM; ++m) p += xu[mf][m] * b2f(xv.s[j*NM + m]);
          af.s[j] = f2b(p);
        }
        #pragma unroll
        for (int hf = 0; hf < 4; ++hf)
          acc[mf][hf] = mfma16(af.v, as_bf(bv[hf]), acc[mf][hf]);
      }
    }
  }
}

__global__ __launch_bounds__(256,2) void k_fwd(const float* __restrict__ t,
                                               const uint4* __restrict__ bfwd,
                                               float* __restrict__ hpre)
{
  __shared__ __align__(16) unsigned char smem[51200];
  unsigned short* lx = (unsigned short*)smem;
  const int nb = blockIdx.x*128;
  const int wv = threadIdx.x>>6, lane = threadIdx.x&63;
  const int slot = blockIdx.y*4 + wv;
  const int quad = lane>>4, col = lane&15;

  f32x4 acc[8][4];
  #pragma unroll
  for (int a = 0; a < 8; ++a)
    #pragma unroll
    for (int b = 0; b < 4; ++b) acc[a][b] = (f32x4){0.f,0.f,0.f,0.f};

  load_tile<0>(t, nb, lx); __syncthreads();
  fwd_region<0>(lx, bfwd, slot, lane, acc); __syncthreads();
  load_tile<1>(t, nb, lx); __syncthreads();
  fwd_region<1>(lx, bfwd, slot, lane, acc); __syncthreads();
  load_tile<2>(t, nb, lx); __syncthreads();
  fwd_region<2>(lx, bfwd, slot, lane, acc); __syncthreads();

  // block-reduce 4 waves' partials in LDS, then one atomicAdd per element
  float* red = (float*)smem;
  for (int tw = 0; tw < 4; ++tw) {
    if (wv == tw) {
      #pragma unroll
      for (int mf = 0; mf < 8; ++mf)
        #pragma unroll
        for (int hf = 0; hf < 4; ++hf)
          #pragma unroll
          for (int rr = 0; rr < 4; ++rr) {
            int idx = (mf*16 + quad*4 + rr)*64 + hf*16 + col;
            if (tw == 0) red[idx] = acc[mf][hf][rr]; else red[idx] += acc[mf][hf][rr];
          }
    }
    __syncthreads();
  }
  for (int i = threadIdx.x; i < 8192; i += 256)
    atomicAdd(&hpre[(size_t)(nb + (i>>6))*64 + (i&63)], red[i]);
}

// ============================================================================
// K2: MLP fwd + bwd.  lane = sample (64/block), 4 waves split the 64 outputs.
// All weight accesses are wave-uniform -> scalar loads. LDS buffers are
// transposed [feat][sample] so both write and full-vector read are conflict-free.
// ============================================================================
__global__ __launch_bounds__(256) void k_mlp(
    const float* __restrict__ hpre,
    const float* __restrict__ w1, const float* __restrict__ b1,
    const float* __restrict__ w2, const float* __restrict__ b2,
    const float* __restrict__ w3, const float* __restrict__ b3,
    const float* __restrict__ w1t, const float* __restrict__ w2t, const float* __restrict__ w3t,
    float* __restrict__ xout, unsigned short* __restrict__ dhb)
{
  __shared__ float Bh1[64*64];            // h1, later reused for g1
  __shared__ float Bh2[64*64];
  __shared__ float Bg2[64*64];
  __shared__ unsigned short Bsp1[64*64];  // silu'(a1) as bf16
  const int n  = threadIdx.x & 63;
  const int wv = threadIdx.x >> 6;
  const int jb = __builtin_amdgcn_readfirstlane(wv*16);
  const int nb = blockIdx.x*64;
  const size_t row = (size_t)(nb + n)*64;

  float h[64];
  #pragma unroll
  for (int i = 0; i < 64; ++i) h[i] = hpre[row + i];

  float dh2r[16];
  #pragma unroll
  for (int jj = 0; jj < 16; ++jj) {
    int j = jb + jj; float s = 0.f;
    #pragma unroll
    for (int z = 0; z < 64; ++z) s += w3[j*64+z];
    dh2r[jj] = s;
  }
  // phase 1: a1 = h@w1+b1
  #pragma unroll
  for (int jj = 0; jj < 16; ++jj) {
    int j = jb + jj; float a = b1[j];
    #pragma unroll
    for (int i = 0; i < 64; ++i) a += h[i]*w1t[j*64+i];
    float sg = 1.f/(1.f + __expf(-a));
    Bh1[j*64+n] = a*sg;
    Bsp1[j*64+n] = f2b(sg*(1.f + a*(1.f-sg)));
  }
  __syncthreads();
  float h1[64];
  #pragma unroll
  for (int i = 0; i < 64; ++i) h1[i] = Bh1[i*64+n];
  // phase 2: a2 = h1@w2+b2 ; g2 = dh2 * silu'(a2)
  #pragma unroll
  for (int jj = 0; jj < 16; ++jj) {
    int j = jb + jj; float a = b2[j];
    #pragma unroll
    for (int i = 0; i < 64; ++i) a += h1[i]*w2t[j*64+i];
    float sg = 1.f/(1.f + __expf(-a));
    Bh2[j*64+n] = a*sg;
    Bg2[j*64+n] = dh2r[jj]*(sg*(1.f + a*(1.f-sg)));
  }
  __syncthreads();
  // phase 3: out = h2@w3+b3 ; dh1 = g2@w2^T ; g1 = dh1*sp1
  float h2[64];
  #pragma unroll
  for (int i = 0; i < 64; ++i) h2[i] = Bh2[i*64+n];
  #pragma unroll
  for (int jj = 0; jj < 16; ++jj) {
    int j = jb + jj; float a = b3[j];
    #pragma unroll
    for (int i = 0; i < 64; ++i) a += h2[i]*w3t[j*64+i];
    xout[row + j] = a;
  }
  float g2[64];
  #pragma unroll
  for (int i = 0; i < 64; ++i) g2[i] = Bg2[i*64+n];
  #pragma unroll
  for (int jj = 0; jj < 16; ++jj) {
    int i = jb + jj; float a = 0.f;
    #pragma unroll
    for (int z = 0; z < 64; ++z) a += g2[z]*w2[i*64+z];
    Bh1[i*64+n] = a * b2f(Bsp1[i*64+n]);   // g1 (reuse Bh1)
  }
  __syncthreads();
  // phase 4: dh = g1@w1^T
  float g1[64];
  #pragma unroll
  for (int i = 0; i < 64; ++i) g1[i] = Bh1[i*64+n];
  #pragma unroll
  for (int jj = 0; jj < 16; ++jj) {
    int i = jb + jj; float a = 0.f;
    #pragma unroll
    for (int z = 0; z < 64; ++z) a += g1[z]*w1[i*64+z];
    dhb[row + i] = f2b(a);
  }
}

// ============================================================================
// K3: backward TP.  dGsym[k,n] = Bbwd @ dh^T (MFMA, A=Bbwd rows, B=dh resident),
// epilogue contracts with x over v in-register; quad-shuffle reduce; write y.
// ============================================================================
template<int R>
DEVI void bwd_region(const unsigned short* lx, const uint4* __restrict__ ba,
                     const uint4 (&bq)[8][2], int slot, int lane,
                     float* __restrict__ y, int nb)
{
  constexpr int NM = RC<R>::NM;
  const int quad = lane>>4, col = lane&15;
  for (int u = slot; u < RC<R>::ROWS; u += 16) {
    float gacc[8][NM];
    #pragma unroll
    for (int nf = 0; nf < 8; ++nf)
      #pragma unroll
      for (int m = 0; m < NM; ++m) gacc[nf][m] = 0.f;

    #pragma unroll
    for (int c = 0; c < RC<R>::NCH; ++c) {
      uint4 aq[2][2];
      #pragma unroll
      for (int kf = 0; kf < 2; ++kf)
        #pragma unroll
        for (int kc = 0; kc < 2; ++kc) {
          int kb = RC<R>::KBASE + u*(2*RC<R>::NCH) + c*2 + kf;
          aq[kf][kc] = ba[(size_t)(kb*2+kc)*64 + lane];
        }
      #pragma unroll
      for (int kf = 0; kf < 2; ++kf) {
        const int v0 = c*32 + kf*16 + quad*4;
        #pragma unroll
        for (int nf = 0; nf < 8; ++nf) {
          f32x4 a4 = (f32x4){0.f,0.f,0.f,0.f};
          a4 = mfma16(as_bf(aq[kf][0]), as_bf(bq[nf][0]), a4);
          a4 = mfma16(as_bf(aq[kf][1]), as_bf(bq[nf][1]), a4);
          const unsigned short* xp = lx + (nf*16+col)*RC<R>::STRIDE + v0*NM;
          union { unsigned short s[4*NM]; ushort4 q[NM]; } xv;
          #pragma unroll
          for (int q = 0; q < NM; ++q) xv.q[q] = reinterpret_cast<const ushort4*>(xp)[q];
          #pragma unroll
          for (int rr = 0; rr < 4; ++rr)
            #pragma unroll
            for (int m = 0; m < NM; ++m)
              gacc[nf][m] += a4[rr] * b2f(xv.s[rr*NM + m]);
        }
      }
    }
    // reduce over quads (v-offsets) and write grad
    #pragma unroll
    for (int nf = 0; nf < 8; ++nf)
      #pragma unroll
      for (int m = 0; m < NM; ++m) {
        float v = gacc[nf][m];
        v += __shfl_down(v, 32, 64);
        v += __shfl_down(v, 16, 64);
        if (lane < 16)
          y[(size_t)(nb + nf*16 + lane)*TDIM + RC<R>::OUT + u*NM + m] = v;
      }
  }
}

__global__ __launch_bounds__(256,2) void k_bwd(const float* __restrict__ t,
                                               const uint4* __restrict__ bbwd,
                                               const unsigned short* __restrict__ dh,
                                               float* __restrict__ y)
{
  __shared__ __align__(16) unsigned char smem[51200];
  unsigned short* lx = (unsigned short*)smem;
  const int nb = blockIdx.x*128;
  const int wv = threadIdx.x>>6, lane = threadIdx.x&63;
  const int slot = blockIdx.y*4 + wv;
  const int quad = lane>>4, col = lane&15;

  uint4 bq[8][2];   // resident dh B-frags: B[h][n]
  #pragma unroll
  for (int nf = 0; nf < 8; ++nf)
    #pragma unroll
    for (int kc = 0; kc < 2; ++kc)
      bq[nf][kc] = *reinterpret_cast<const uint4*>(dh + (size_t)(nb + nf*16 + col)*64 + kc*32 + quad*8);

  load_tile<0>(t, nb, lx); __syncthreads();
  bwd_region<0>(lx, bbwd, bq, slot, lane, y, nb); __syncthreads();
  load_tile<1>(t, nb, lx); __syncthreads();
  bwd_region<1>(lx, bbwd, bq, slot, lane, y, nb); __syncthreads();
  load_tile<2>(t, nb, lx); __syncthreads();
  bwd_region<2>(lx, bbwd, bq, slot, lane, y, nb);
}

// ============================================================================
extern "C" void kernel_launch(void* const* d_in, const int* in_sizes, int n_in,
                              void* d_out, int out_size, void* d_ws, size_t ws_size,
                              hipStream_t stream) {
  (void)in_sizes; (void)n_in; (void)out_size; (void)ws_size;
  const float* t  = (const float*)d_in[0];
  const float* W0 = (const float*)d_in[1];
  const float* W1 = (const float*)d_in[2];
  const float* W2 = (const float*)d_in[3];
  const float* w1 = (const float*)d_in[4];
  const float* b1 = (const float*)d_in[5];
  const float* w2 = (const float*)d_in[6];
  const float* b2 = (const float*)d_in[7];
  const float* w3 = (const float*)d_in[8];
  const float* b3 = (const float*)d_in[9];

  char* ws = (char*)d_ws;
  unsigned short* bfwd = (unsigned short*)(ws + O_BFWD);
  unsigned short* bbwd = (unsigned short*)(ws + O_BBWD);
  float*          hpre = (float*)(ws + O_HPRE);
  unsigned short* dhb  = (unsigned short*)(ws + O_DH);
  float*          w1t  = (float*)(ws + O_W1T);
  float*          w2t  = (float*)(ws + O_W2T);
  float*          w3t  = (float*)(ws + O_W3T);

  float* xout = (float*)d_out;
  float* y    = (float*)d_out + (size_t)NSAMP*64;

  k_prep<<<dim3(5376), dim3(256), 0, stream>>>(W0, W1, W2, w1, w2, w3,
                                               bfwd, bbwd, hpre, w1t, w2t, w3t);
  k_fwd <<<dim3(128,4), dim3(256), 0, stream>>>(t, (const uint4*)bfwd, hpre);
  k_mlp <<<dim3(256), dim3(256), 0, stream>>>(hpre, w1, b1, w2, b2, w3, b3,
                                              w1t, w2t, w3t, xout, dhb);
  k_bwd <<<dim3(128,4), dim3(256), 0, stream>>>(t, (const uint4*)bbwd, dhb, y);
}

// Round 2
// 1904.438 us; speedup vs baseline: 1.2263x; 1.2263x over previous
//
#include <hip/hip_runtime.h>
#include <hip/hip_bf16.h>

typedef short bf16x8 __attribute__((ext_vector_type(8)));
typedef float f32x4  __attribute__((ext_vector_type(4)));

#define DEVI __device__ __forceinline__

static constexpr int    NSAMP = 16384;
static constexpr int    TDIM  = 480;
static constexpr int    KTOT  = 21504;

// ---- workspace layout (bytes) ----
// gws (f32 [480][16384], 31.5 MB) aliases bfwd+hpre4: both are dead before
// k_bwd writes gws.  Order: prep->fwd(reads bfwd, writes hpre4)->mlp(reads
// hpre4, writes dh)->bwd(reads bbwd+dh, writes gws)->tr(reads gws, writes y).
static constexpr size_t SZ_B   = (size_t)KTOT * 64 * 2;            // 2,752,512
static constexpr size_t O_GWS  = 0;                                // 31,457,280
static constexpr size_t O_BFWD = 0;                                // aliases gws
static constexpr size_t O_HPRE = O_BFWD + SZ_B;                    // f32 [4][N][64] = 16.8MB, aliases gws
static constexpr size_t O_BBWD = (size_t)TDIM * NSAMP * 4;         // after gws
static constexpr size_t O_DH   = O_BBWD + SZ_B;                    // bf16 N*64
static constexpr size_t O_W1T  = O_DH   + (size_t)NSAMP*64*2;
static constexpr size_t O_W2T  = O_W1T + (size_t)64*64*4;
static constexpr size_t O_W3T  = O_W2T + (size_t)64*64*4;
// total ~36.3 MB

DEVI float b2f(unsigned short s) { union { unsigned u; float f; } v; v.u = (unsigned)s << 16; return v.f; }
DEVI unsigned short f2b(float f) { union { __hip_bfloat16 h; unsigned short s; } v; v.h = __float2bfloat16(f); return v.s; }
DEVI bf16x8 as_bf(uint4 q) { union { uint4 q; bf16x8 v; } u; u.q = q; return u.v; }
DEVI f32x4 mfma16(bf16x8 a, bf16x8 b, f32x4 c) { return __builtin_amdgcn_mfma_f32_16x16x32_bf16(a, b, c, 0, 0, 0); }

// region config: r0 = l0 (128x128), r1 = l1 (64x64, m=3), r2 = l2 (32x32, m=5)
template<int R> struct RC;
template<> struct RC<0> { static constexpr int COLS=128, OFF=0,   STRIDE=136, ROWS=128, NCH=4, NM=1, CBASE=0,   KBASE=0,    OUT=0;   };
template<> struct RC<1> { static constexpr int COLS=192, OFF=128, STRIDE=200, ROWS=64,  NCH=2, NM=3, CBASE=512, KBASE=1024, OUT=128; };
template<> struct RC<2> { static constexpr int COLS=160, OFF=320, STRIDE=168, ROWS=32,  NCH=1, NM=5, CBASE=640, KBASE=1280, OUT=320; };

// ============================================================================
// K0: weight prep.  Bfwd (frag-major for fwd GEMM B-operand), Bbwd (frag-major
// symmetrized, for bwd GEMM A-operand), transpose w1/w2/w3.
// ============================================================================
__global__ __launch_bounds__(256) void k_prep(
    const float* __restrict__ W0, const float* __restrict__ W1, const float* __restrict__ W2,
    const float* __restrict__ w1, const float* __restrict__ w2, const float* __restrict__ w3,
    unsigned short* __restrict__ bfwd, unsigned short* __restrict__ bbwd,
    float* __restrict__ w1t, float* __restrict__ w2t, float* __restrict__ w3t)
{
  const int e = blockIdx.x*256 + threadIdx.x;
  const float CA = 0.0068192924f;   // 1/sqrt(21504)
  const float C1 = 0.0039371205f;   // CA/sqrt(3)
  const float C2 = 0.0030496940f;   // CA/sqrt(5)
  if (e < KTOT*64) {
    { // forward B: frag (chunk=32k x 16h); lane holds B[k=quad*8+j][h=hf*16+col]
      int j = e & 7, lane = (e>>3)&63, hf = (e>>9)&3, chunk = e>>11;
      int k = chunk*32 + (lane>>4)*8 + j;
      int h = hf*16 + (lane&15);
      float v;
      if (k < 16384)      v = CA * W0[(size_t)k*64 + h];
      else if (k < 20480) v = C1 * W1[(size_t)(k-16384)*64 + h];
      else                v = C2 * W2[(size_t)(k-20480)*64 + h];
      bfwd[e] = f2b(v);
    }
    { // backward A: frag (16 k-rows x 32 h); lane holds A[k=kb*16+col][h=kc*32+quad*8+j]
      int j = e & 7, lane = (e>>3)&63, kc = (e>>9)&1, kb = e>>10;
      int k = kb*16 + (lane&15);
      int h = kc*32 + (lane>>4)*8 + j;
      float v;
      if (k < 16384)      { int u=k>>7,    vv=k&127;          v = CA*(W0[(size_t)(u*128+vv)*64+h] + W0[(size_t)(vv*128+u)*64+h]); }
      else if (k < 20480) { int l=k-16384; int u=l>>6, vv=l&63; v = C1*(W1[(size_t)(u*64+vv)*64+h] + W1[(size_t)(vv*64+u)*64+h]); }
      else                { int l=k-20480; int u=l>>5, vv=l&31; v = C2*(W2[(size_t)(u*32+vv)*64+h] + W2[(size_t)(vv*32+u)*64+h]); }
      bbwd[e] = f2b(v);
    }
  }
  if (e < 4096) {
    int i = e>>6, j = e&63;
    w1t[j*64+i] = w1[e]; w2t[j*64+i] = w2[e]; w3t[j*64+i] = w3[e];
  }
}

// ---- cooperative x-tile loader: 128 samples x COLS, f32 global -> bf16 LDS ----
template<int R>
DEVI void load_tile(const float* __restrict__ t, int nb, unsigned short* lx)
{
  const int tid = threadIdx.x;
  const int s = tid >> 1, half = tid & 1;
  constexpr int CH = RC<R>::COLS/2;
  const float4* src = reinterpret_cast<const float4*>(t + (size_t)(nb+s)*TDIM + RC<R>::OFF + half*CH);
  unsigned short* dst = lx + s*RC<R>::STRIDE + half*CH;
  #pragma unroll
  for (int e4 = 0; e4 < CH/4; ++e4) {
    float4 v = src[e4];
    ushort4 o; o.x = f2b(v.x); o.y = f2b(v.y); o.z = f2b(v.z); o.w = f2b(v.w);
    *reinterpret_cast<ushort4*>(dst + e4*4) = o;
  }
}

// ============================================================================
// K1: forward TP.  C[n(128/wave), h(64)] += Gram(x) @ Bfwd over this slot's
// k-rows.  A built on the fly: A[n, (u,v)] = sum_m x[n,u,m]*x[n,v,m].
// grid (128 tiles, 4 ksplit) x 256 thr; each ksplit writes its own hpre slice
// (plain coalesced stores, no atomics); k_mlp sums the 4 slices.
// ============================================================================
template<int R>
DEVI void fwd_region(const unsigned short* lx, const uint4* __restrict__ bf,
                     int slot, int lane, f32x4 (&acc)[8][4])
{
  constexpr int NM = RC<R>::NM;
  const int quad = lane>>4, col = lane&15;
  for (int u = slot; u < RC<R>::ROWS; u += 16) {
    float xu[8][NM];
    #pragma unroll
    for (int mf = 0; mf < 8; ++mf) {
      const unsigned short* row = lx + (mf*16+col)*RC<R>::STRIDE + u*NM;
      #pragma unroll
      for (int m = 0; m < NM; ++m) xu[mf][m] = b2f(row[m]);
    }
    #pragma unroll
    for (int c = 0; c < RC<R>::NCH; ++c) {
      const int chunk = RC<R>::CBASE + u*RC<R>::NCH + c;
      uint4 bv[4];
      #pragma unroll
      for (int hf = 0; hf < 4; ++hf) bv[hf] = bf[(size_t)(chunk*4 + hf)*64 + lane];
      #pragma unroll
      for (int mf = 0; mf < 8; ++mf) {
        const uint4* xp4 = reinterpret_cast<const uint4*>(
            lx + (mf*16+col)*RC<R>::STRIDE + (c*32 + quad*8)*NM);
        union { unsigned short s[8*NM]; uint4 q[NM]; } xv;
        #pragma unroll
        for (int q = 0; q < NM; ++q) xv.q[q] = xp4[q];
        union { unsigned short s[8]; bf16x8 v; } af;
        #pragma unroll
        for (int j = 0; j < 8; ++j) {
          float p = 0.f;
          #pragma unroll
          for (int m = 0; m < NM; ++m) p += xu[mf][m] * b2f(xv.s[j*NM + m]);
          af.s[j] = f2b(p);
        }
        #pragma unroll
        for (int hf = 0; hf < 4; ++hf)
          acc[mf][hf] = mfma16(af.v, as_bf(bv[hf]), acc[mf][hf]);
      }
    }
  }
}

__global__ __launch_bounds__(256,2) void k_fwd(const float* __restrict__ t,
                                               const uint4* __restrict__ bfwd,
                                               float* __restrict__ hpre)
{
  __shared__ __align__(16) unsigned char smem[51200];
  unsigned short* lx = (unsigned short*)smem;
  const int nb = blockIdx.x*128;
  const int wv = threadIdx.x>>6, lane = threadIdx.x&63;
  const int slot = blockIdx.y*4 + wv;
  const int quad = lane>>4, col = lane&15;

  f32x4 acc[8][4];
  #pragma unroll
  for (int a = 0; a < 8; ++a)
    #pragma unroll
    for (int b = 0; b < 4; ++b) acc[a][b] = (f32x4){0.f,0.f,0.f,0.f};

  load_tile<0>(t, nb, lx); __syncthreads();
  fwd_region<0>(lx, bfwd, slot, lane, acc); __syncthreads();
  load_tile<1>(t, nb, lx); __syncthreads();
  fwd_region<1>(lx, bfwd, slot, lane, acc); __syncthreads();
  load_tile<2>(t, nb, lx); __syncthreads();
  fwd_region<2>(lx, bfwd, slot, lane, acc); __syncthreads();

  // block-reduce 4 waves' partials in LDS, then plain coalesced store into
  // this ksplit's hpre slice
  float* red = (float*)smem;
  for (int tw = 0; tw < 4; ++tw) {
    if (wv == tw) {
      #pragma unroll
      for (int mf = 0; mf < 8; ++mf)
        #pragma unroll
        for (int hf = 0; hf < 4; ++hf)
          #pragma unroll
          for (int rr = 0; rr < 4; ++rr) {
            int idx = (mf*16 + quad*4 + rr)*64 + hf*16 + col;
            if (tw == 0) red[idx] = acc[mf][hf][rr]; else red[idx] += acc[mf][hf][rr];
          }
    }
    __syncthreads();
  }
  float* hp = hpre + (size_t)blockIdx.y*NSAMP*64;
  for (int i = threadIdx.x; i < 8192; i += 256)
    hp[(size_t)(nb + (i>>6))*64 + (i&63)] = red[i];
}

// ============================================================================
// K2: MLP fwd + bwd.  lane = sample (64/block), 4 waves split the 64 outputs.
// Sums the 4 ksplit hpre slices on load.
// ============================================================================
__global__ __launch_bounds__(256) void k_mlp(
    const float* __restrict__ hpre,
    const float* __restrict__ w1, const float* __restrict__ b1,
    const float* __restrict__ w2, const float* __restrict__ b2,
    const float* __restrict__ w3, const float* __restrict__ b3,
    const float* __restrict__ w1t, const float* __restrict__ w2t, const float* __restrict__ w3t,
    float* __restrict__ xout, unsigned short* __restrict__ dhb)
{
  __shared__ float Bh1[64*64];            // h1, later reused for g1
  __shared__ float Bh2[64*64];
  __shared__ float Bg2[64*64];
  __shared__ unsigned short Bsp1[64*64];  // silu'(a1) as bf16
  const int n  = threadIdx.x & 63;
  const int wv = threadIdx.x >> 6;
  const int jb = __builtin_amdgcn_readfirstlane(wv*16);
  const int nb = blockIdx.x*64;
  const size_t row = (size_t)(nb + n)*64;

  float h[64];
  #pragma unroll
  for (int i = 0; i < 64; ++i)
    h[i] = hpre[row + i] + hpre[(size_t)NSAMP*64 + row + i]
         + hpre[(size_t)2*NSAMP*64 + row + i] + hpre[(size_t)3*NSAMP*64 + row + i];

  float dh2r[16];
  #pragma unroll
  for (int jj = 0; jj < 16; ++jj) {
    int j = jb + jj; float s = 0.f;
    #pragma unroll
    for (int z = 0; z < 64; ++z) s += w3[j*64+z];
    dh2r[jj] = s;
  }
  // phase 1: a1 = h@w1+b1
  #pragma unroll
  for (int jj = 0; jj < 16; ++jj) {
    int j = jb + jj; float a = b1[j];
    #pragma unroll
    for (int i = 0; i < 64; ++i) a += h[i]*w1t[j*64+i];
    float sg = 1.f/(1.f + __expf(-a));
    Bh1[j*64+n] = a*sg;
    Bsp1[j*64+n] = f2b(sg*(1.f + a*(1.f-sg)));
  }
  __syncthreads();
  float h1[64];
  #pragma unroll
  for (int i = 0; i < 64; ++i) h1[i] = Bh1[i*64+n];
  // phase 2: a2 = h1@w2+b2 ; g2 = dh2 * silu'(a2)
  #pragma unroll
  for (int jj = 0; jj < 16; ++jj) {
    int j = jb + jj; float a = b2[j];
    #pragma unroll
    for (int i = 0; i < 64; ++i) a += h1[i]*w2t[j*64+i];
    float sg = 1.f/(1.f + __expf(-a));
    Bh2[j*64+n] = a*sg;
    Bg2[j*64+n] = dh2r[jj]*(sg*(1.f + a*(1.f-sg)));
  }
  __syncthreads();
  // phase 3: out = h2@w3+b3 ; dh1 = g2@w2^T ; g1 = dh1*sp1
  float h2[64];
  #pragma unroll
  for (int i = 0; i < 64; ++i) h2[i] = Bh2[i*64+n];
  #pragma unroll
  for (int jj = 0; jj < 16; ++jj) {
    int j = jb + jj; float a = b3[j];
    #pragma unroll
    for (int i = 0; i < 64; ++i) a += h2[i]*w3t[j*64+i];
    xout[row + j] = a;
  }
  float g2[64];
  #pragma unroll
  for (int i = 0; i < 64; ++i) g2[i] = Bg2[i*64+n];
  #pragma unroll
  for (int jj = 0; jj < 16; ++jj) {
    int i = jb + jj; float a = 0.f;
    #pragma unroll
    for (int z = 0; z < 64; ++z) a += g2[z]*w2[i*64+z];
    Bh1[i*64+n] = a * b2f(Bsp1[i*64+n]);   // g1 (reuse Bh1)
  }
  __syncthreads();
  // phase 4: dh = g1@w1^T
  float g1[64];
  #pragma unroll
  for (int i = 0; i < 64; ++i) g1[i] = Bh1[i*64+n];
  #pragma unroll
  for (int jj = 0; jj < 16; ++jj) {
    int i = jb + jj; float a = 0.f;
    #pragma unroll
    for (int z = 0; z < 64; ++z) a += g1[z]*w1[i*64+z];
    dhb[row + i] = f2b(a);
  }
}

// ============================================================================
// K3: backward TP.  dGsym[k,n] = Bbwd @ dh^T (MFMA, A=Bbwd rows, B=dh resident),
// epilogue contracts with x over v in-register; quad-shuffle reduce; store to
// COMPACT column-major gws[col][n]: 16 active lanes = 16 consecutive samples
// = one aligned 64B line per store (vs the old 1920B-stride scatter into y
// that caused 22x write amplification).
// ============================================================================
template<int R>
DEVI void bwd_region(const unsigned short* lx, const uint4* __restrict__ ba,
                     const uint4 (&bq)[8][2], int slot, int lane,
                     float* __restrict__ gws, int nb)
{
  constexpr int NM = RC<R>::NM;
  const int quad = lane>>4, col = lane&15;
  for (int u = slot; u < RC<R>::ROWS; u += 16) {
    float gacc[8][NM];
    #pragma unroll
    for (int nf = 0; nf < 8; ++nf)
      #pragma unroll
      for (int m = 0; m < NM; ++m) gacc[nf][m] = 0.f;

    #pragma unroll
    for (int c = 0; c < RC<R>::NCH; ++c) {
      uint4 aq[2][2];
      #pragma unroll
      for (int kf = 0; kf < 2; ++kf)
        #pragma unroll
        for (int kc = 0; kc < 2; ++kc) {
          int kb = RC<R>::KBASE + u*(2*RC<R>::NCH) + c*2 + kf;
          aq[kf][kc] = ba[(size_t)(kb*2+kc)*64 + lane];
        }
      #pragma unroll
      for (int kf = 0; kf < 2; ++kf) {
        const int v0 = c*32 + kf*16 + quad*4;
        #pragma unroll
        for (int nf = 0; nf < 8; ++nf) {
          f32x4 a4 = (f32x4){0.f,0.f,0.f,0.f};
          a4 = mfma16(as_bf(aq[kf][0]), as_bf(bq[nf][0]), a4);
          a4 = mfma16(as_bf(aq[kf][1]), as_bf(bq[nf][1]), a4);
          const unsigned short* xp = lx + (nf*16+col)*RC<R>::STRIDE + v0*NM;
          union { unsigned short s[4*NM]; ushort4 q[NM]; } xv;
          #pragma unroll
          for (int q = 0; q < NM; ++q) xv.q[q] = reinterpret_cast<const ushort4*>(xp)[q];
          #pragma unroll
          for (int rr = 0; rr < 4; ++rr)
            #pragma unroll
            for (int m = 0; m < NM; ++m)
              gacc[nf][m] += a4[rr] * b2f(xv.s[rr*NM + m]);
        }
      }
    }
    // reduce over quads (v-offsets); 16 lanes store 16 consecutive samples
    #pragma unroll
    for (int nf = 0; nf < 8; ++nf)
      #pragma unroll
      for (int m = 0; m < NM; ++m) {
        float v = gacc[nf][m];
        v += __shfl_down(v, 32, 64);
        v += __shfl_down(v, 16, 64);
        if (lane < 16)
          gws[(size_t)(RC<R>::OUT + u*NM + m)*NSAMP + nb + nf*16 + lane] = v;
      }
  }
}

__global__ __launch_bounds__(256,2) void k_bwd(const float* __restrict__ t,
                                               const uint4* __restrict__ bbwd,
                                               const unsigned short* __restrict__ dh,
                                               float* __restrict__ gws)
{
  __shared__ __align__(16) unsigned char smem[51200];
  unsigned short* lx = (unsigned short*)smem;
  const int nb = blockIdx.x*128;
  const int wv = threadIdx.x>>6, lane = threadIdx.x&63;
  const int slot = blockIdx.y*4 + wv;
  const int quad = lane>>4, col = lane&15;

  uint4 bq[8][2];   // resident dh B-frags: B[h][n]
  #pragma unroll
  for (int nf = 0; nf < 8; ++nf)
    #pragma unroll
    for (int kc = 0; kc < 2; ++kc)
      bq[nf][kc] = *reinterpret_cast<const uint4*>(dh + (size_t)(nb + nf*16 + col)*64 + kc*32 + quad*8);

  load_tile<0>(t, nb, lx); __syncthreads();
  bwd_region<0>(lx, bbwd, bq, slot, lane, gws, nb); __syncthreads();
  load_tile<1>(t, nb, lx); __syncthreads();
  bwd_region<1>(lx, bbwd, bq, slot, lane, gws, nb); __syncthreads();
  load_tile<2>(t, nb, lx); __syncthreads();
  bwd_region<2>(lx, bbwd, bq, slot, lane, gws, nb);
}

// ============================================================================
// K4: transpose gws[480][16384] -> y[16384][480].  512 blocks x 32 samples,
// both sides fully coalesced float4 via an LDS tile.
// ============================================================================
__global__ __launch_bounds__(256) void k_tr(const float* __restrict__ gws,
                                            float* __restrict__ y)
{
  __shared__ float tile[32][481];
  const int n0 = blockIdx.x*32;
  // read: 480 cols x 8 float4 (32 samples)
  for (int idx = threadIdx.x; idx < 480*8; idx += 256) {
    int c = idx >> 3, i4 = idx & 7;
    float4 v = reinterpret_cast<const float4*>(gws + (size_t)c*NSAMP + n0)[i4];
    tile[i4*4+0][c] = v.x; tile[i4*4+1][c] = v.y;
    tile[i4*4+2][c] = v.z; tile[i4*4+3][c] = v.w;
  }
  __syncthreads();
  // write: 32 samples x 120 float4
  for (int idx = threadIdx.x; idx < 32*120; idx += 256) {
    int s = idx/120, c4 = idx%120;
    float4 v = { tile[s][c4*4+0], tile[s][c4*4+1], tile[s][c4*4+2], tile[s][c4*4+3] };
    reinterpret_cast<float4*>(y + (size_t)(n0+s)*TDIM)[c4] = v;
  }
}

// ============================================================================
extern "C" void kernel_launch(void* const* d_in, const int* in_sizes, int n_in,
                              void* d_out, int out_size, void* d_ws, size_t ws_size,
                              hipStream_t stream) {
  (void)in_sizes; (void)n_in; (void)out_size; (void)ws_size;
  const float* t  = (const float*)d_in[0];
  const float* W0 = (const float*)d_in[1];
  const float* W1 = (const float*)d_in[2];
  const float* W2 = (const float*)d_in[3];
  const float* w1 = (const float*)d_in[4];
  const float* b1 = (const float*)d_in[5];
  const float* w2 = (const float*)d_in[6];
  const float* b2 = (const float*)d_in[7];
  const float* w3 = (const float*)d_in[8];
  const float* b3 = (const float*)d_in[9];

  char* ws = (char*)d_ws;
  float*          gws  = (float*)(ws + O_GWS);
  unsigned short* bfwd = (unsigned short*)(ws + O_BFWD);
  unsigned short* bbwd = (unsigned short*)(ws + O_BBWD);
  float*          hpre = (float*)(ws + O_HPRE);
  unsigned short* dhb  = (unsigned short*)(ws + O_DH);
  float*          w1t  = (float*)(ws + O_W1T);
  float*          w2t  = (float*)(ws + O_W2T);
  float*          w3t  = (float*)(ws + O_W3T);

  float* xout = (float*)d_out;
  float* y    = (float*)d_out + (size_t)NSAMP*64;

  k_prep<<<dim3(5376), dim3(256), 0, stream>>>(W0, W1, W2, w1, w2, w3,
                                               bfwd, bbwd, w1t, w2t, w3t);
  k_fwd <<<dim3(128,4), dim3(256), 0, stream>>>(t, (const uint4*)bfwd, hpre);
  k_mlp <<<dim3(256), dim3(256), 0, stream>>>(hpre, w1, b1, w2, b2, w3, b3,
                                              w1t, w2t, w3t, xout, dhb);
  k_bwd <<<dim3(128,4), dim3(256), 0, stream>>>(t, (const uint4*)bbwd, dhb, gws);
  k_tr  <<<dim3(512),   dim3(256), 0, stream>>>(gws, y);
}

// Round 3
// 592.143 us; speedup vs baseline: 3.9439x; 3.2162x over previous
//
#include <hip/hip_runtime.h>
#include <hip/hip_bf16.h>

typedef short bf16x8 __attribute__((ext_vector_type(8)));
typedef float f32x4  __attribute__((ext_vector_type(4)));

#define DEVI __device__ __forceinline__

static constexpr int    NSAMP = 16384;
static constexpr int    TDIM  = 480;
static constexpr int    KTOT  = 21504;

// ---- workspace layout (bytes) ----
static constexpr size_t SZ_B   = (size_t)KTOT * 64 * 2;            // 2,752,512
static constexpr size_t O_GWS  = 0;                                // 31,457,280
static constexpr size_t O_BFWD = 0;                                // aliases gws (dead before k_bwd)
static constexpr size_t O_HPRE = O_BFWD + SZ_B;                    // f32 [4][N][64], aliases gws
static constexpr size_t O_BBWD = (size_t)TDIM * NSAMP * 4;         // after gws
static constexpr size_t O_DH   = O_BBWD + SZ_B;                    // bf16 N*64
static constexpr size_t O_W1T  = O_DH   + (size_t)NSAMP*64*2;
static constexpr size_t O_W2T  = O_W1T + (size_t)64*64*4;
static constexpr size_t O_W3T  = O_W2T + (size_t)64*64*4;

DEVI float b2f(unsigned short s) { union { unsigned u; float f; } v; v.u = (unsigned)s << 16; return v.f; }
DEVI unsigned short f2b(float f) { union { __hip_bfloat16 h; unsigned short s; } v; v.h = __float2bfloat16(f); return v.s; }
DEVI bf16x8 as_bf(uint4 q) { union { uint4 q; bf16x8 v; } u; u.q = q; return u.v; }
DEVI f32x4 mfma16(bf16x8 a, bf16x8 b, f32x4 c) { return __builtin_amdgcn_mfma_f32_16x16x32_bf16(a, b, c, 0, 0, 0); }

template<int R> struct RC;
template<> struct RC<0> { static constexpr int COLS=128, OFF=0,   STRIDE=136, ROWS=128, NCH=4, NM=1, CBASE=0,   KBASE=0,    OUT=0;   };
template<> struct RC<1> { static constexpr int COLS=192, OFF=128, STRIDE=200, ROWS=64,  NCH=2, NM=3, CBASE=512, KBASE=1024, OUT=128; };
template<> struct RC<2> { static constexpr int COLS=160, OFF=320, STRIDE=168, ROWS=32,  NCH=1, NM=5, CBASE=640, KBASE=1280, OUT=320; };

// ============================================================================
// K0: weight prep.
// ============================================================================
__global__ __launch_bounds__(256) void k_prep(
    const float* __restrict__ W0, const float* __restrict__ W1, const float* __restrict__ W2,
    const float* __restrict__ w1, const float* __restrict__ w2, const float* __restrict__ w3,
    unsigned short* __restrict__ bfwd, unsigned short* __restrict__ bbwd,
    float* __restrict__ w1t, float* __restrict__ w2t, float* __restrict__ w3t)
{
  const int e = blockIdx.x*256 + threadIdx.x;
  const float CA = 0.0068192924f;   // 1/sqrt(21504)
  const float C1 = 0.0039371205f;   // CA/sqrt(3)
  const float C2 = 0.0030496940f;   // CA/sqrt(5)
  if (e < KTOT*64) {
    { // forward B: lane holds B[k=quad*8+j][h=hf*16+col]
      int j = e & 7, lane = (e>>3)&63, hf = (e>>9)&3, chunk = e>>11;
      int k = chunk*32 + (lane>>4)*8 + j;
      int h = hf*16 + (lane&15);
      float v;
      if (k < 16384)      v = CA * W0[(size_t)k*64 + h];
      else if (k < 20480) v = C1 * W1[(size_t)(k-16384)*64 + h];
      else                v = C2 * W2[(size_t)(k-20480)*64 + h];
      bfwd[e] = f2b(v);
    }
    { // backward A (symmetrized): lane holds A[k=kb*16+col][h=kc*32+quad*8+j]
      int j = e & 7, lane = (e>>3)&63, kc = (e>>9)&1, kb = e>>10;
      int k = kb*16 + (lane&15);
      int h = kc*32 + (lane>>4)*8 + j;
      float v;
      if (k < 16384)      { int u=k>>7,    vv=k&127;          v = CA*(W0[(size_t)(u*128+vv)*64+h] + W0[(size_t)(vv*128+u)*64+h]); }
      else if (k < 20480) { int l=k-16384; int u=l>>6, vv=l&63; v = C1*(W1[(size_t)(u*64+vv)*64+h] + W1[(size_t)(vv*64+u)*64+h]); }
      else                { int l=k-20480; int u=l>>5, vv=l&31; v = C2*(W2[(size_t)(u*32+vv)*64+h] + W2[(size_t)(vv*32+u)*64+h]); }
      bbwd[e] = f2b(v);
    }
  }
  if (e < 4096) {
    int i = e>>6, j = e&63;
    w1t[j*64+i] = w1[e]; w2t[j*64+i] = w2[e]; w3t[j*64+i] = w3[e];
  }
}

// ---- cooperative x-tile loader: 128 samples x COLS, f32 global -> bf16 LDS ----
template<int R>
DEVI void load_tile(const float* __restrict__ t, int nb, unsigned short* lx)
{
  const int tid = threadIdx.x;
  const int s = tid >> 1, half = tid & 1;
  constexpr int CH = RC<R>::COLS/2;
  const float4* src = reinterpret_cast<const float4*>(t + (size_t)(nb+s)*TDIM + RC<R>::OFF + half*CH);
  unsigned short* dst = lx + s*RC<R>::STRIDE + half*CH;
  #pragma unroll
  for (int e4 = 0; e4 < CH/4; ++e4) {
    float4 v = src[e4];
    ushort4 o; o.x = f2b(v.x); o.y = f2b(v.y); o.z = f2b(v.z); o.w = f2b(v.w);
    *reinterpret_cast<ushort4*>(dst + e4*4) = o;
  }
}

// ============================================================================
// K1: forward TP.  c-loop NOT unrolled (register pressure: keep only one
// chunk's 4 B-frags live); xu loaded per-mf (not pre-staged [8][NM]).
// ============================================================================
template<int R>
DEVI void fwd_region(const unsigned short* lx, const uint4* __restrict__ bf,
                     int slot, int lane, f32x4 (&acc)[8][4])
{
  constexpr int NM = RC<R>::NM;
  const int quad = lane>>4, col = lane&15;
  for (int u = slot; u < RC<R>::ROWS; u += 16) {
    #pragma unroll 1
    for (int c = 0; c < RC<R>::NCH; ++c) {
      const int chunk = RC<R>::CBASE + u*RC<R>::NCH + c;
      uint4 bv[4];
      #pragma unroll
      for (int hf = 0; hf < 4; ++hf) bv[hf] = bf[(size_t)(chunk*4 + hf)*64 + lane];
      #pragma unroll
      for (int mf = 0; mf < 8; ++mf) {
        const unsigned short* rowp = lx + (mf*16+col)*RC<R>::STRIDE;
        float xu[NM];
        #pragma unroll
        for (int m = 0; m < NM; ++m) xu[m] = b2f(rowp[u*NM + m]);
        const uint4* xp4 = reinterpret_cast<const uint4*>(rowp + (c*32 + quad*8)*NM);
        union { unsigned short s[8*NM]; uint4 q[NM]; } xv;
        #pragma unroll
        for (int q = 0; q < NM; ++q) xv.q[q] = xp4[q];
        union { unsigned short s[8]; bf16x8 v; } af;
        #pragma unroll
        for (int j = 0; j < 8; ++j) {
          float p = 0.f;
          #pragma unroll
          for (int m = 0; m < NM; ++m) p += xu[m] * b2f(xv.s[j*NM + m]);
          af.s[j] = f2b(p);
        }
        #pragma unroll
        for (int hf = 0; hf < 4; ++hf)
          acc[mf][hf] = mfma16(af.v, as_bf(bv[hf]), acc[mf][hf]);
      }
    }
  }
}

__global__ __launch_bounds__(256,2) void k_fwd(const float* __restrict__ t,
                                               const uint4* __restrict__ bfwd,
                                               float* __restrict__ hpre)
{
  __shared__ __align__(16) unsigned char smem[51200];
  unsigned short* lx = (unsigned short*)smem;
  const int nb = blockIdx.x*128;
  const int wv = threadIdx.x>>6, lane = threadIdx.x&63;
  const int slot = blockIdx.y*4 + wv;
  const int quad = lane>>4, col = lane&15;

  f32x4 acc[8][4];
  #pragma unroll
  for (int a = 0; a < 8; ++a)
    #pragma unroll
    for (int b = 0; b < 4; ++b) acc[a][b] = (f32x4){0.f,0.f,0.f,0.f};

  load_tile<0>(t, nb, lx); __syncthreads();
  fwd_region<0>(lx, bfwd, slot, lane, acc); __syncthreads();
  load_tile<1>(t, nb, lx); __syncthreads();
  fwd_region<1>(lx, bfwd, slot, lane, acc); __syncthreads();
  load_tile<2>(t, nb, lx); __syncthreads();
  fwd_region<2>(lx, bfwd, slot, lane, acc); __syncthreads();

  float* red = (float*)smem;
  for (int tw = 0; tw < 4; ++tw) {
    if (wv == tw) {
      #pragma unroll
      for (int mf = 0; mf < 8; ++mf)
        #pragma unroll
        for (int hf = 0; hf < 4; ++hf)
          #pragma unroll
          for (int rr = 0; rr < 4; ++rr) {
            int idx = (mf*16 + quad*4 + rr)*64 + hf*16 + col;
            if (tw == 0) red[idx] = acc[mf][hf][rr]; else red[idx] += acc[mf][hf][rr];
          }
    }
    __syncthreads();
  }
  float* hp = hpre + (size_t)blockIdx.y*NSAMP*64;
  for (int i = threadIdx.x; i < 8192; i += 256)
    hp[(size_t)(nb + (i>>6))*64 + (i&63)] = red[i];
}

// ============================================================================
// K2: MLP fwd + bwd (sums 4 ksplit hpre slices on load).
// ============================================================================
__global__ __launch_bounds__(256) void k_mlp(
    const float* __restrict__ hpre,
    const float* __restrict__ w1, const float* __restrict__ b1,
    const float* __restrict__ w2, const float* __restrict__ b2,
    const float* __restrict__ w3, const float* __restrict__ b3,
    const float* __restrict__ w1t, const float* __restrict__ w2t, const float* __restrict__ w3t,
    float* __restrict__ xout, unsigned short* __restrict__ dhb)
{
  __shared__ float Bh1[64*64];
  __shared__ float Bh2[64*64];
  __shared__ float Bg2[64*64];
  __shared__ unsigned short Bsp1[64*64];
  const int n  = threadIdx.x & 63;
  const int wv = threadIdx.x >> 6;
  const int jb = __builtin_amdgcn_readfirstlane(wv*16);
  const int nb = blockIdx.x*64;
  const size_t row = (size_t)(nb + n)*64;

  float h[64];
  #pragma unroll
  for (int i = 0; i < 64; ++i)
    h[i] = hpre[row + i] + hpre[(size_t)NSAMP*64 + row + i]
         + hpre[(size_t)2*NSAMP*64 + row + i] + hpre[(size_t)3*NSAMP*64 + row + i];

  float dh2r[16];
  #pragma unroll
  for (int jj = 0; jj < 16; ++jj) {
    int j = jb + jj; float s = 0.f;
    #pragma unroll
    for (int z = 0; z < 64; ++z) s += w3[j*64+z];
    dh2r[jj] = s;
  }
  #pragma unroll
  for (int jj = 0; jj < 16; ++jj) {
    int j = jb + jj; float a = b1[j];
    #pragma unroll
    for (int i = 0; i < 64; ++i) a += h[i]*w1t[j*64+i];
    float sg = 1.f/(1.f + __expf(-a));
    Bh1[j*64+n] = a*sg;
    Bsp1[j*64+n] = f2b(sg*(1.f + a*(1.f-sg)));
  }
  __syncthreads();
  float h1[64];
  #pragma unroll
  for (int i = 0; i < 64; ++i) h1[i] = Bh1[i*64+n];
  #pragma unroll
  for (int jj = 0; jj < 16; ++jj) {
    int j = jb + jj; float a = b2[j];
    #pragma unroll
    for (int i = 0; i < 64; ++i) a += h1[i]*w2t[j*64+i];
    float sg = 1.f/(1.f + __expf(-a));
    Bh2[j*64+n] = a*sg;
    Bg2[j*64+n] = dh2r[jj]*(sg*(1.f + a*(1.f-sg)));
  }
  __syncthreads();
  float h2[64];
  #pragma unroll
  for (int i = 0; i < 64; ++i) h2[i] = Bh2[i*64+n];
  #pragma unroll
  for (int jj = 0; jj < 16; ++jj) {
    int j = jb + jj; float a = b3[j];
    #pragma unroll
    for (int i = 0; i < 64; ++i) a += h2[i]*w3t[j*64+i];
    xout[row + j] = a;
  }
  float g2[64];
  #pragma unroll
  for (int i = 0; i < 64; ++i) g2[i] = Bg2[i*64+n];
  #pragma unroll
  for (int jj = 0; jj < 16; ++jj) {
    int i = jb + jj; float a = 0.f;
    #pragma unroll
    for (int z = 0; z < 64; ++z) a += g2[z]*w2[i*64+z];
    Bh1[i*64+n] = a * b2f(Bsp1[i*64+n]);
  }
  __syncthreads();
  float g1[64];
  #pragma unroll
  for (int i = 0; i < 64; ++i) g1[i] = Bh1[i*64+n];
  #pragma unroll
  for (int jj = 0; jj < 16; ++jj) {
    int i = jb + jj; float a = 0.f;
    #pragma unroll
    for (int z = 0; z < 64; ++z) a += g1[z]*w1[i*64+z];
    dhb[row + i] = f2b(a);
  }
}

// ============================================================================
// K3: backward TP.  dh B-frags live in LDS (16 KB, loaded once) instead of
// 64 resident VGPRs; c-loop not unrolled.  This kernel was spilling ~600 MB
// of scratch per dispatch (WRITE_SIZE 630 MB vs 31.5 MB of program stores).
// ============================================================================
template<int R>
DEVI void bwd_region(const unsigned short* lx, const unsigned char* dhl,
                     const uint4* __restrict__ ba, int slot, int lane,
                     float* __restrict__ gws, int nb)
{
  constexpr int NM = RC<R>::NM;
  const int quad = lane>>4, col = lane&15;
  for (int u = slot; u < RC<R>::ROWS; u += 16) {
    float gacc[8][NM];
    #pragma unroll
    for (int nf = 0; nf < 8; ++nf)
      #pragma unroll
      for (int m = 0; m < NM; ++m) gacc[nf][m] = 0.f;

    #pragma unroll 1
    for (int c = 0; c < RC<R>::NCH; ++c) {
      uint4 aq[2][2];
      #pragma unroll
      for (int kf = 0; kf < 2; ++kf)
        #pragma unroll
        for (int kc = 0; kc < 2; ++kc) {
          int kb = RC<R>::KBASE + u*(2*RC<R>::NCH) + c*2 + kf;
          aq[kf][kc] = ba[(size_t)(kb*2+kc)*64 + lane];
        }
      #pragma unroll
      for (int kf = 0; kf < 2; ++kf) {
        const int v0 = c*32 + kf*16 + quad*4;
        #pragma unroll
        for (int nf = 0; nf < 8; ++nf) {
          uint4 b0 = *reinterpret_cast<const uint4*>(dhl + ((size_t)(nf*2+0)*64 + lane)*16);
          uint4 b1 = *reinterpret_cast<const uint4*>(dhl + ((size_t)(nf*2+1)*64 + lane)*16);
          f32x4 a4 = (f32x4){0.f,0.f,0.f,0.f};
          a4 = mfma16(as_bf(aq[kf][0]), as_bf(b0), a4);
          a4 = mfma16(as_bf(aq[kf][1]), as_bf(b1), a4);
          const unsigned short* xp = lx + (nf*16+col)*RC<R>::STRIDE + v0*NM;
          union { unsigned short s[4*NM]; ushort4 q[NM]; } xv;
          #pragma unroll
          for (int q = 0; q < NM; ++q) xv.q[q] = reinterpret_cast<const ushort4*>(xp)[q];
          #pragma unroll
          for (int rr = 0; rr < 4; ++rr)
            #pragma unroll
            for (int m = 0; m < NM; ++m)
              gacc[nf][m] += a4[rr] * b2f(xv.s[rr*NM + m]);
        }
      }
    }
    #pragma unroll
    for (int nf = 0; nf < 8; ++nf)
      #pragma unroll
      for (int m = 0; m < NM; ++m) {
        float v = gacc[nf][m];
        v += __shfl_down(v, 32, 64);
        v += __shfl_down(v, 16, 64);
        if (lane < 16)
          gws[(size_t)(RC<R>::OUT + u*NM + m)*NSAMP + nb + nf*16 + lane] = v;
      }
  }
}

__global__ __launch_bounds__(256,2) void k_bwd(const float* __restrict__ t,
                                               const uint4* __restrict__ bbwd,
                                               const unsigned short* __restrict__ dh,
                                               float* __restrict__ gws)
{
  // 51200 B x-tile (max region) + 16384 B dh-fragment tile (persistent)
  __shared__ __align__(16) unsigned char smem[67584];
  unsigned short* lx = (unsigned short*)smem;
  unsigned char*  dhl = smem + 51200;
  const int nb = blockIdx.x*128;
  const int wv = threadIdx.x>>6, lane = threadIdx.x&63;
  const int slot = blockIdx.y*4 + wv;

  // stage dh B-frags into LDS once: entry e=(nf*2+kc)*64+lane, 16B each
  for (int e = threadIdx.x; e < 1024; e += 256) {
    int nf = e >> 7, kc = (e >> 6) & 1, ln = e & 63;
    int cl = ln & 15, qd = ln >> 4;
    uint4 v = *reinterpret_cast<const uint4*>(dh + (size_t)(nb + nf*16 + cl)*64 + kc*32 + qd*8);
    *reinterpret_cast<uint4*>(dhl + (size_t)e*16) = v;
  }

  load_tile<0>(t, nb, lx); __syncthreads();
  bwd_region<0>(lx, dhl, bbwd, slot, lane, gws, nb); __syncthreads();
  load_tile<1>(t, nb, lx); __syncthreads();
  bwd_region<1>(lx, dhl, bbwd, slot, lane, gws, nb); __syncthreads();
  load_tile<2>(t, nb, lx); __syncthreads();
  bwd_region<2>(lx, dhl, bbwd, slot, lane, gws, nb);
}

// ============================================================================
// K4: transpose gws[480][16384] -> y[16384][480], coalesced both sides.
// ============================================================================
__global__ __launch_bounds__(256) void k_tr(const float* __restrict__ gws,
                                            float* __restrict__ y)
{
  __shared__ float tile[32][481];
  const int n0 = blockIdx.x*32;
  for (int idx = threadIdx.x; idx < 480*8; idx += 256) {
    int c = idx >> 3, i4 = idx & 7;
    float4 v = reinterpret_cast<const float4*>(gws + (size_t)c*NSAMP + n0)[i4];
    tile[i4*4+0][c] = v.x; tile[i4*4+1][c] = v.y;
    tile[i4*4+2][c] = v.z; tile[i4*4+3][c] = v.w;
  }
  __syncthreads();
  for (int idx = threadIdx.x; idx < 32*120; idx += 256) {
    int s = idx/120, c4 = idx%120;
    float4 v = { tile[s][c4*4+0], tile[s][c4*4+1], tile[s][c4*4+2], tile[s][c4*4+3] };
    reinterpret_cast<float4*>(y + (size_t)(n0+s)*TDIM)[c4] = v;
  }
}

// ============================================================================
extern "C" void kernel_launch(void* const* d_in, const int* in_sizes, int n_in,
                              void* d_out, int out_size, void* d_ws, size_t ws_size,
                              hipStream_t stream) {
  (void)in_sizes; (void)n_in; (void)out_size; (void)ws_size;
  const float* t  = (const float*)d_in[0];
  const float* W0 = (const float*)d_in[1];
  const float* W1 = (const float*)d_in[2];
  const float* W2 = (const float*)d_in[3];
  const float* w1 = (const float*)d_in[4];
  const float* b1 = (const float*)d_in[5];
  const float* w2 = (const float*)d_in[6];
  const float* b2 = (const float*)d_in[7];
  const float* w3 = (const float*)d_in[8];
  const float* b3 = (const float*)d_in[9];

  char* ws = (char*)d_ws;
  float*          gws  = (float*)(ws + O_GWS);
  unsigned short* bfwd = (unsigned short*)(ws + O_BFWD);
  unsigned short* bbwd = (unsigned short*)(ws + O_BBWD);
  float*          hpre = (float*)(ws + O_HPRE);
  unsigned short* dhb  = (unsigned short*)(ws + O_DH);
  float*          w1t  = (float*)(ws + O_W1T);
  float*          w2t  = (float*)(ws + O_W2T);
  float*          w3t  = (float*)(ws + O_W3T);

  float* xout = (float*)d_out;
  float* y    = (float*)d_out + (size_t)NSAMP*64;

  k_prep<<<dim3(5376), dim3(256), 0, stream>>>(W0, W1, W2, w1, w2, w3,
                                               bfwd, bbwd, w1t, w2t, w3t);
  k_fwd <<<dim3(128,4), dim3(256), 0, stream>>>(t, (const uint4*)bfwd, hpre);
  k_mlp <<<dim3(256), dim3(256), 0, stream>>>(hpre, w1, b1, w2, b2, w3, b3,
                                              w1t, w2t, w3t, xout, dhb);
  k_bwd <<<dim3(128,4), dim3(256), 0, stream>>>(t, (const uint4*)bbwd, dhb, gws);
  k_tr  <<<dim3(512),   dim3(256), 0, stream>>>(gws, y);
}

// Round 4
// 397.101 us; speedup vs baseline: 5.8810x; 1.4912x over previous
//
#include <hip/hip_runtime.h>
#include <hip/hip_bf16.h>

typedef short bf16x8 __attribute__((ext_vector_type(8)));
typedef float f32x4  __attribute__((ext_vector_type(4)));

#define DEVI __device__ __forceinline__

static constexpr int    NSAMP = 16384;
static constexpr int    TDIM  = 480;
static constexpr int    KTOT  = 21504;

// ---- workspace layout (bytes) ----
static constexpr size_t SZ_B   = (size_t)KTOT * 64 * 2;            // 2,752,512
static constexpr size_t O_GWS  = 0;                                // 31,457,280
static constexpr size_t O_BFWD = 0;                                // aliases gws (dead before k_bwd)
static constexpr size_t O_HPRE = O_BFWD + SZ_B;                    // f32 [4][N][64], aliases gws
static constexpr size_t O_BBWD = (size_t)TDIM * NSAMP * 4;         // after gws
static constexpr size_t O_DH   = O_BBWD + SZ_B;                    // bf16 N*64
static constexpr size_t O_W1T  = O_DH   + (size_t)NSAMP*64*2;
static constexpr size_t O_W2T  = O_W1T + (size_t)64*64*4;
static constexpr size_t O_W3T  = O_W2T + (size_t)64*64*4;

DEVI float b2f(unsigned short s) { union { unsigned u; float f; } v; v.u = (unsigned)s << 16; return v.f; }
DEVI unsigned short f2b(float f) { union { __hip_bfloat16 h; unsigned short s; } v; v.h = __float2bfloat16(f); return v.s; }
DEVI bf16x8 as_bf(uint4 q) { union { uint4 q; bf16x8 v; } u; u.q = q; return u.v; }
DEVI f32x4 mfma16(bf16x8 a, bf16x8 b, f32x4 c) { return __builtin_amdgcn_mfma_f32_16x16x32_bf16(a, b, c, 0, 0, 0); }

// pure-SSA bf16 element extraction (no unions -> no alloca risk)
template<int NQ>
DEVI float x4_at(const uint4 (&q)[NQ], int e) {   // e in [0, 8*NQ)
  const uint4 qq = q[e>>3];
  const int wi = (e>>1)&3;
  unsigned w = wi==0?qq.x: wi==1?qq.y: wi==2?qq.z: qq.w;
  return b2f((unsigned short)((e&1)? (w>>16) : w));
}
template<int NQ>
DEVI float x2_at(const uint2 (&q)[NQ], int e) {   // e in [0, 4*NQ)
  const uint2 qq = q[e>>2];
  unsigned w = ((e>>1)&1)? qq.y : qq.x;
  return b2f((unsigned short)((e&1)? (w>>16) : w));
}

template<int R> struct RC;
template<> struct RC<0> { static constexpr int COLS=128, OFF=0,   STRIDE=136, ROWS=128, NCH=4, NM=1, CBASE=0,   KBASE=0,    OUT=0;   };
template<> struct RC<1> { static constexpr int COLS=192, OFF=128, STRIDE=200, ROWS=64,  NCH=2, NM=3, CBASE=512, KBASE=1024, OUT=128; };
template<> struct RC<2> { static constexpr int COLS=160, OFF=320, STRIDE=168, ROWS=32,  NCH=1, NM=5, CBASE=640, KBASE=1280, OUT=320; };

// ============================================================================
// K0: weight prep.
// ============================================================================
__global__ __launch_bounds__(256) void k_prep(
    const float* __restrict__ W0, const float* __restrict__ W1, const float* __restrict__ W2,
    const float* __restrict__ w1, const float* __restrict__ w2, const float* __restrict__ w3,
    unsigned short* __restrict__ bfwd, unsigned short* __restrict__ bbwd,
    float* __restrict__ w1t, float* __restrict__ w2t, float* __restrict__ w3t)
{
  const int e = blockIdx.x*256 + threadIdx.x;
  const float CA = 0.0068192924f;   // 1/sqrt(21504)
  const float C1 = 0.0039371205f;   // CA/sqrt(3)
  const float C2 = 0.0030496940f;   // CA/sqrt(5)
  if (e < KTOT*64) {
    { // forward B: lane holds B[k=quad*8+j][h=hf*16+col]
      int j = e & 7, lane = (e>>3)&63, hf = (e>>9)&3, chunk = e>>11;
      int k = chunk*32 + (lane>>4)*8 + j;
      int h = hf*16 + (lane&15);
      float v;
      if (k < 16384)      v = CA * W0[(size_t)k*64 + h];
      else if (k < 20480) v = C1 * W1[(size_t)(k-16384)*64 + h];
      else                v = C2 * W2[(size_t)(k-20480)*64 + h];
      bfwd[e] = f2b(v);
    }
    { // backward A (symmetrized): lane holds A[k=kb*16+col][h=kc*32+quad*8+j]
      int j = e & 7, lane = (e>>3)&63, kc = (e>>9)&1, kb = e>>10;
      int k = kb*16 + (lane&15);
      int h = kc*32 + (lane>>4)*8 + j;
      float v;
      if (k < 16384)      { int u=k>>7,    vv=k&127;          v = CA*(W0[(size_t)(u*128+vv)*64+h] + W0[(size_t)(vv*128+u)*64+h]); }
      else if (k < 20480) { int l=k-16384; int u=l>>6, vv=l&63; v = C1*(W1[(size_t)(u*64+vv)*64+h] + W1[(size_t)(vv*64+u)*64+h]); }
      else                { int l=k-20480; int u=l>>5, vv=l&31; v = C2*(W2[(size_t)(u*32+vv)*64+h] + W2[(size_t)(vv*32+u)*64+h]); }
      bbwd[e] = f2b(v);
    }
  }
  if (e < 4096) {
    int i = e>>6, j = e&63;
    w1t[j*64+i] = w1[e]; w2t[j*64+i] = w2[e]; w3t[j*64+i] = w3[e];
  }
}

// ---- cooperative x-tile loader: 64 samples x COLS, f32 global -> bf16 LDS ----
template<int R>
DEVI void load_tile(const float* __restrict__ t, int nb, unsigned short* lx)
{
  const int tid = threadIdx.x;
  const int s = tid >> 2, p = tid & 3;          // row, quarter
  constexpr int CH = RC<R>::COLS/4;             // 32 / 48 / 40
  const float4* src = reinterpret_cast<const float4*>(t + (size_t)(nb+s)*TDIM + RC<R>::OFF + p*CH);
  unsigned short* dst = lx + s*RC<R>::STRIDE + p*CH;
  #pragma unroll
  for (int e4 = 0; e4 < CH/4; ++e4) {
    float4 v = src[e4];
    ushort4 o; o.x = f2b(v.x); o.y = f2b(v.y); o.z = f2b(v.z); o.w = f2b(v.w);
    *reinterpret_cast<ushort4*>(dst + e4*4) = o;
  }
}

// ============================================================================
// K1: forward TP, 64-sample tiles (acc[4][4] = 64 regs; was 128 -> spilled).
// ============================================================================
template<int R>
DEVI void fwd_region(const unsigned short* lx, const uint4* __restrict__ bf,
                     int slot, int lane, f32x4 (&acc)[4][4])
{
  constexpr int NM = RC<R>::NM;
  const int quad = lane>>4, col = lane&15;
  for (int u = slot; u < RC<R>::ROWS; u += 16) {
    #pragma unroll 1
    for (int c = 0; c < RC<R>::NCH; ++c) {
      const int chunk = RC<R>::CBASE + u*RC<R>::NCH + c;
      uint4 bv[4];
      #pragma unroll
      for (int hf = 0; hf < 4; ++hf) bv[hf] = bf[(size_t)(chunk*4 + hf)*64 + lane];
      #pragma unroll
      for (int mf = 0; mf < 4; ++mf) {
        const unsigned short* rowp = lx + (mf*16+col)*RC<R>::STRIDE;
        float xu[NM];
        #pragma unroll
        for (int m = 0; m < NM; ++m) xu[m] = b2f(rowp[u*NM + m]);
        uint4 xq[NM];
        const uint4* xp4 = reinterpret_cast<const uint4*>(rowp + (c*32 + quad*8)*NM);
        #pragma unroll
        for (int q = 0; q < NM; ++q) xq[q] = xp4[q];
        unsigned aw[4];
        #pragma unroll
        for (int jp = 0; jp < 4; ++jp) {
          float p0 = 0.f, p1 = 0.f;
          #pragma unroll
          for (int m = 0; m < NM; ++m) {
            p0 += xu[m] * x4_at(xq, (2*jp+0)*NM + m);
            p1 += xu[m] * x4_at(xq, (2*jp+1)*NM + m);
          }
          aw[jp] = (unsigned)f2b(p0) | ((unsigned)f2b(p1) << 16);
        }
        uint4 afq; afq.x = aw[0]; afq.y = aw[1]; afq.z = aw[2]; afq.w = aw[3];
        #pragma unroll
        for (int hf = 0; hf < 4; ++hf)
          acc[mf][hf] = mfma16(as_bf(afq), as_bf(bv[hf]), acc[mf][hf]);
      }
    }
  }
}

__global__ __launch_bounds__(256,2) void k_fwd(const float* __restrict__ t,
                                               const uint4* __restrict__ bfwd,
                                               float* __restrict__ hpre)
{
  __shared__ __align__(16) unsigned char smem[25600];  // max x-tile (r1); red[16KB] aliases
  unsigned short* lx = (unsigned short*)smem;
  const int nb = blockIdx.x*64;
  const int wv = threadIdx.x>>6, lane = threadIdx.x&63;
  const int slot = blockIdx.y*4 + wv;
  const int quad = lane>>4, col = lane&15;

  f32x4 acc[4][4];
  #pragma unroll
  for (int a = 0; a < 4; ++a)
    #pragma unroll
    for (int b = 0; b < 4; ++b) acc[a][b] = (f32x4){0.f,0.f,0.f,0.f};

  load_tile<0>(t, nb, lx); __syncthreads();
  fwd_region<0>(lx, bfwd, slot, lane, acc); __syncthreads();
  load_tile<1>(t, nb, lx); __syncthreads();
  fwd_region<1>(lx, bfwd, slot, lane, acc); __syncthreads();
  load_tile<2>(t, nb, lx); __syncthreads();
  fwd_region<2>(lx, bfwd, slot, lane, acc); __syncthreads();

  float* red = (float*)smem;                 // 64x64 f32 = 16 KB
  for (int tw = 0; tw < 4; ++tw) {
    if (wv == tw) {
      #pragma unroll
      for (int mf = 0; mf < 4; ++mf)
        #pragma unroll
        for (int hf = 0; hf < 4; ++hf)
          #pragma unroll
          for (int rr = 0; rr < 4; ++rr) {
            int idx = (mf*16 + quad*4 + rr)*64 + hf*16 + col;
            if (tw == 0) red[idx] = acc[mf][hf][rr]; else red[idx] += acc[mf][hf][rr];
          }
    }
    __syncthreads();
  }
  float* hp = hpre + (size_t)blockIdx.y*NSAMP*64;
  for (int i = threadIdx.x; i < 4096; i += 256)
    hp[(size_t)(nb + (i>>6))*64 + (i&63)] = red[i];
}

// ============================================================================
// K2: MLP fwd + bwd (sums 4 ksplit hpre slices on load).
// ============================================================================
__global__ __launch_bounds__(256) void k_mlp(
    const float* __restrict__ hpre,
    const float* __restrict__ w1, const float* __restrict__ b1,
    const float* __restrict__ w2, const float* __restrict__ b2,
    const float* __restrict__ w3, const float* __restrict__ b3,
    const float* __restrict__ w1t, const float* __restrict__ w2t, const float* __restrict__ w3t,
    float* __restrict__ xout, unsigned short* __restrict__ dhb)
{
  __shared__ float Bh1[64*64];
  __shared__ float Bh2[64*64];
  __shared__ float Bg2[64*64];
  __shared__ unsigned short Bsp1[64*64];
  const int n  = threadIdx.x & 63;
  const int wv = threadIdx.x >> 6;
  const int jb = __builtin_amdgcn_readfirstlane(wv*16);
  const int nb = blockIdx.x*64;
  const size_t row = (size_t)(nb + n)*64;

  float h[64];
  #pragma unroll
  for (int i = 0; i < 64; ++i)
    h[i] = hpre[row + i] + hpre[(size_t)NSAMP*64 + row + i]
         + hpre[(size_t)2*NSAMP*64 + row + i] + hpre[(size_t)3*NSAMP*64 + row + i];

  float dh2r[16];
  #pragma unroll
  for (int jj = 0; jj < 16; ++jj) {
    int j = jb + jj; float s = 0.f;
    #pragma unroll
    for (int z = 0; z < 64; ++z) s += w3[j*64+z];
    dh2r[jj] = s;
  }
  #pragma unroll
  for (int jj = 0; jj < 16; ++jj) {
    int j = jb + jj; float a = b1[j];
    #pragma unroll
    for (int i = 0; i < 64; ++i) a += h[i]*w1t[j*64+i];
    float sg = 1.f/(1.f + __expf(-a));
    Bh1[j*64+n] = a*sg;
    Bsp1[j*64+n] = f2b(sg*(1.f + a*(1.f-sg)));
  }
  __syncthreads();
  float h1[64];
  #pragma unroll
  for (int i = 0; i < 64; ++i) h1[i] = Bh1[i*64+n];
  #pragma unroll
  for (int jj = 0; jj < 16; ++jj) {
    int j = jb + jj; float a = b2[j];
    #pragma unroll
    for (int i = 0; i < 64; ++i) a += h1[i]*w2t[j*64+i];
    float sg = 1.f/(1.f + __expf(-a));
    Bh2[j*64+n] = a*sg;
    Bg2[j*64+n] = dh2r[jj]*(sg*(1.f + a*(1.f-sg)));
  }
  __syncthreads();
  float h2[64];
  #pragma unroll
  for (int i = 0; i < 64; ++i) h2[i] = Bh2[i*64+n];
  #pragma unroll
  for (int jj = 0; jj < 16; ++jj) {
    int j = jb + jj; float a = b3[j];
    #pragma unroll
    for (int i = 0; i < 64; ++i) a += h2[i]*w3t[j*64+i];
    xout[row + j] = a;
  }
  float g2[64];
  #pragma unroll
  for (int i = 0; i < 64; ++i) g2[i] = Bg2[i*64+n];
  #pragma unroll
  for (int jj = 0; jj < 16; ++jj) {
    int i = jb + jj; float a = 0.f;
    #pragma unroll
    for (int z = 0; z < 64; ++z) a += g2[z]*w2[i*64+z];
    Bh1[i*64+n] = a * b2f(Bsp1[i*64+n]);
  }
  __syncthreads();
  float g1[64];
  #pragma unroll
  for (int i = 0; i < 64; ++i) g1[i] = Bh1[i*64+n];
  #pragma unroll
  for (int jj = 0; jj < 16; ++jj) {
    int i = jb + jj; float a = 0.f;
    #pragma unroll
    for (int z = 0; z < 64; ++z) a += g1[z]*w1[i*64+z];
    dhb[row + i] = f2b(a);
  }
}

// ============================================================================
// K3: backward TP, 64-sample tiles (gacc[4][NM] <= 20 regs; dh frags in LDS).
// ============================================================================
template<int R>
DEVI void bwd_region(const unsigned short* lx, const unsigned char* dhl,
                     const uint4* __restrict__ ba, int slot, int lane,
                     float* __restrict__ gws, int nb)
{
  constexpr int NM = RC<R>::NM;
  const int quad = lane>>4, col = lane&15;
  for (int u = slot; u < RC<R>::ROWS; u += 16) {
    float gacc[4][NM];
    #pragma unroll
    for (int nf = 0; nf < 4; ++nf)
      #pragma unroll
      for (int m = 0; m < NM; ++m) gacc[nf][m] = 0.f;

    #pragma unroll 1
    for (int c = 0; c < RC<R>::NCH; ++c) {
      uint4 aq[2][2];
      #pragma unroll
      for (int kf = 0; kf < 2; ++kf)
        #pragma unroll
        for (int kc = 0; kc < 2; ++kc) {
          int kb = RC<R>::KBASE + u*(2*RC<R>::NCH) + c*2 + kf;
          aq[kf][kc] = ba[(size_t)(kb*2+kc)*64 + lane];
        }
      #pragma unroll
      for (int kf = 0; kf < 2; ++kf) {
        const int v0 = c*32 + kf*16 + quad*4;
        #pragma unroll
        for (int nf = 0; nf < 4; ++nf) {
          uint4 b0 = *reinterpret_cast<const uint4*>(dhl + ((size_t)(nf*2+0)*64 + lane)*16);
          uint4 b1 = *reinterpret_cast<const uint4*>(dhl + ((size_t)(nf*2+1)*64 + lane)*16);
          f32x4 a4 = (f32x4){0.f,0.f,0.f,0.f};
          a4 = mfma16(as_bf(aq[kf][0]), as_bf(b0), a4);
          a4 = mfma16(as_bf(aq[kf][1]), as_bf(b1), a4);
          const unsigned short* xp = lx + (nf*16+col)*RC<R>::STRIDE + v0*NM;
          uint2 xq[NM];
          const uint2* xp2 = reinterpret_cast<const uint2*>(xp);
          #pragma unroll
          for (int q = 0; q < NM; ++q) xq[q] = xp2[q];
          #pragma unroll
          for (int rr = 0; rr < 4; ++rr)
            #pragma unroll
            for (int m = 0; m < NM; ++m)
              gacc[nf][m] += a4[rr] * x2_at(xq, rr*NM + m);
        }
      }
    }
    #pragma unroll
    for (int nf = 0; nf < 4; ++nf)
      #pragma unroll
      for (int m = 0; m < NM; ++m) {
        float v = gacc[nf][m];
        v += __shfl_down(v, 32, 64);
        v += __shfl_down(v, 16, 64);
        if (lane < 16)
          gws[(size_t)(RC<R>::OUT + u*NM + m)*NSAMP + nb + nf*16 + lane] = v;
      }
  }
}

__global__ __launch_bounds__(256,2) void k_bwd(const float* __restrict__ t,
                                               const uint4* __restrict__ bbwd,
                                               const unsigned short* __restrict__ dh,
                                               float* __restrict__ gws)
{
  // 25600 B x-tile (max region) + 8192 B dh-fragment tile (persistent)
  __shared__ __align__(16) unsigned char smem[33792];
  unsigned short* lx = (unsigned short*)smem;
  unsigned char*  dhl = smem + 25600;
  const int nb = blockIdx.x*64;
  const int wv = threadIdx.x>>6, lane = threadIdx.x&63;
  const int slot = blockIdx.y*4 + wv;

  // stage dh B-frags into LDS once: entry e=(nf*2+kc)*64+lane, 16B each
  for (int e = threadIdx.x; e < 512; e += 256) {
    int nf = e >> 7, kc = (e >> 6) & 1, ln = e & 63;
    int cl = ln & 15, qd = ln >> 4;
    uint4 v = *reinterpret_cast<const uint4*>(dh + (size_t)(nb + nf*16 + cl)*64 + kc*32 + qd*8);
    *reinterpret_cast<uint4*>(dhl + (size_t)e*16) = v;
  }

  load_tile<0>(t, nb, lx); __syncthreads();
  bwd_region<0>(lx, dhl, bbwd, slot, lane, gws, nb); __syncthreads();
  load_tile<1>(t, nb, lx); __syncthreads();
  bwd_region<1>(lx, dhl, bbwd, slot, lane, gws, nb); __syncthreads();
  load_tile<2>(t, nb, lx); __syncthreads();
  bwd_region<2>(lx, dhl, bbwd, slot, lane, gws, nb);
}

// ============================================================================
// K4: transpose gws[480][16384] -> y[16384][480], coalesced both sides.
// ============================================================================
__global__ __launch_bounds__(256) void k_tr(const float* __restrict__ gws,
                                            float* __restrict__ y)
{
  __shared__ float tile[32][481];
  const int n0 = blockIdx.x*32;
  for (int idx = threadIdx.x; idx < 480*8; idx += 256) {
    int c = idx >> 3, i4 = idx & 7;
    float4 v = reinterpret_cast<const float4*>(gws + (size_t)c*NSAMP + n0)[i4];
    tile[i4*4+0][c] = v.x; tile[i4*4+1][c] = v.y;
    tile[i4*4+2][c] = v.z; tile[i4*4+3][c] = v.w;
  }
  __syncthreads();
  for (int idx = threadIdx.x; idx < 32*120; idx += 256) {
    int s = idx/120, c4 = idx%120;
    float4 v = { tile[s][c4*4+0], tile[s][c4*4+1], tile[s][c4*4+2], tile[s][c4*4+3] };
    reinterpret_cast<float4*>(y + (size_t)(n0+s)*TDIM)[c4] = v;
  }
}

// ============================================================================
extern "C" void kernel_launch(void* const* d_in, const int* in_sizes, int n_in,
                              void* d_out, int out_size, void* d_ws, size_t ws_size,
                              hipStream_t stream) {
  (void)in_sizes; (void)n_in; (void)out_size; (void)ws_size;
  const float* t  = (const float*)d_in[0];
  const float* W0 = (const float*)d_in[1];
  const float* W1 = (const float*)d_in[2];
  const float* W2 = (const float*)d_in[3];
  const float* w1 = (const float*)d_in[4];
  const float* b1 = (const float*)d_in[5];
  const float* w2 = (const float*)d_in[6];
  const float* b2 = (const float*)d_in[7];
  const float* w3 = (const float*)d_in[8];
  const float* b3 = (const float*)d_in[9];

  char* ws = (char*)d_ws;
  float*          gws  = (float*)(ws + O_GWS);
  unsigned short* bfwd = (unsigned short*)(ws + O_BFWD);
  unsigned short* bbwd = (unsigned short*)(ws + O_BBWD);
  float*          hpre = (float*)(ws + O_HPRE);
  unsigned short* dhb  = (unsigned short*)(ws + O_DH);
  float*          w1t  = (float*)(ws + O_W1T);
  float*          w2t  = (float*)(ws + O_W2T);
  float*          w3t  = (float*)(ws + O_W3T);

  float* xout = (float*)d_out;
  float* y    = (float*)d_out + (size_t)NSAMP*64;

  k_prep<<<dim3(5376), dim3(256), 0, stream>>>(W0, W1, W2, w1, w2, w3,
                                               bfwd, bbwd, w1t, w2t, w3t);
  k_fwd <<<dim3(256,4), dim3(256), 0, stream>>>(t, (const uint4*)bfwd, hpre);
  k_mlp <<<dim3(256), dim3(256), 0, stream>>>(hpre, w1, b1, w2, b2, w3, b3,
                                              w1t, w2t, w3t, xout, dhb);
  k_bwd <<<dim3(256,4), dim3(256), 0, stream>>>(t, (const uint4*)bbwd, dhb, gws);
  k_tr  <<<dim3(512),   dim3(256), 0, stream>>>(gws, y);
}

// Round 6
// 393.866 us; speedup vs baseline: 5.9293x; 1.0082x over previous
//
#include <hip/hip_runtime.h>
#include <hip/hip_bf16.h>

typedef short bf16x8 __attribute__((ext_vector_type(8)));
typedef float f32x4  __attribute__((ext_vector_type(4)));

#define DEVI __device__ __forceinline__

static constexpr int    NSAMP = 16384;
static constexpr int    TDIM  = 480;
static constexpr int    KTOT  = 21504;

// ---- workspace layout (bytes) ----
static constexpr size_t SZ_B   = (size_t)KTOT * 64 * 2;            // 2,752,512
static constexpr size_t O_GWS  = 0;                                // 31,457,280
static constexpr size_t O_BFWD = 0;                                // aliases gws (dead before k_bwd)
static constexpr size_t O_HPRE = O_BFWD + SZ_B;                    // f32 [4][N][64], aliases gws
static constexpr size_t O_BBWD = (size_t)TDIM * NSAMP * 4;         // after gws
static constexpr size_t O_DH   = O_BBWD + SZ_B;                    // bf16 N*64
static constexpr size_t O_W1T  = O_DH   + (size_t)NSAMP*64*2;
static constexpr size_t O_W2T  = O_W1T + (size_t)64*64*4;
static constexpr size_t O_W3T  = O_W2T + (size_t)64*64*4;

DEVI float b2f(unsigned short s) { union { unsigned u; float f; } v; v.u = (unsigned)s << 16; return v.f; }
DEVI unsigned short f2b(float f) { union { __hip_bfloat16 h; unsigned short s; } v; v.h = __float2bfloat16(f); return v.s; }
DEVI bf16x8 as_bf(uint4 q) { union { uint4 q; bf16x8 v; } u; u.q = q; return u.v; }
DEVI f32x4 mfma16(bf16x8 a, bf16x8 b, f32x4 c) { return __builtin_amdgcn_mfma_f32_16x16x32_bf16(a, b, c, 0, 0, 0); }

// pure-SSA bf16 element extraction (no unions -> no alloca risk)
template<int NQ>
DEVI float x4_at(const uint4 (&q)[NQ], int e) {   // e in [0, 8*NQ)
  const uint4 qq = q[e>>3];
  const int wi = (e>>1)&3;
  unsigned w = wi==0?qq.x: wi==1?qq.y: wi==2?qq.z: qq.w;
  return b2f((unsigned short)((e&1)? (w>>16) : w));
}
template<int NQ>
DEVI float x2_at(const uint2 (&q)[NQ], int e) {   // e in [0, 4*NQ)
  const uint2 qq = q[e>>2];
  unsigned w = ((e>>1)&1)? qq.y : qq.x;
  return b2f((unsigned short)((e&1)? (w>>16) : w));
}

template<int R> struct RC;
template<> struct RC<0> { static constexpr int COLS=128, OFF=0,   STRIDE=136, ROWS=128, NCH=4, NM=1, CBASE=0,   KBASE=0,    OUT=0;   };
template<> struct RC<1> { static constexpr int COLS=192, OFF=128, STRIDE=200, ROWS=64,  NCH=2, NM=3, CBASE=512, KBASE=1024, OUT=128; };
template<> struct RC<2> { static constexpr int COLS=160, OFF=320, STRIDE=168, ROWS=32,  NCH=1, NM=5, CBASE=640, KBASE=1280, OUT=320; };

// ============================================================================
// K0: weight prep.
// ============================================================================
__global__ __launch_bounds__(256) void k_prep(
    const float* __restrict__ W0, const float* __restrict__ W1, const float* __restrict__ W2,
    const float* __restrict__ w1, const float* __restrict__ w2, const float* __restrict__ w3,
    unsigned short* __restrict__ bfwd, unsigned short* __restrict__ bbwd,
    float* __restrict__ w1t, float* __restrict__ w2t, float* __restrict__ w3t)
{
  const int e = blockIdx.x*256 + threadIdx.x;
  const float CA = 0.0068192924f;   // 1/sqrt(21504)
  const float C1 = 0.0039371205f;   // CA/sqrt(3)
  const float C2 = 0.0030496940f;   // CA/sqrt(5)
  if (e < KTOT*64) {
    { // forward B: lane holds B[k=quad*8+j][h=hf*16+col]
      int j = e & 7, lane = (e>>3)&63, hf = (e>>9)&3, chunk = e>>11;
      int k = chunk*32 + (lane>>4)*8 + j;
      int h = hf*16 + (lane&15);
      float v;
      if (k < 16384)      v = CA * W0[(size_t)k*64 + h];
      else if (k < 20480) v = C1 * W1[(size_t)(k-16384)*64 + h];
      else                v = C2 * W2[(size_t)(k-20480)*64 + h];
      bfwd[e] = f2b(v);
    }
    { // backward A (symmetrized): lane holds A[k=kb*16+col][h=kc*32+quad*8+j]
      int j = e & 7, lane = (e>>3)&63, kc = (e>>9)&1, kb = e>>10;
      int k = kb*16 + (lane&15);
      int h = kc*32 + (lane>>4)*8 + j;
      float v;
      if (k < 16384)      { int u=k>>7,    vv=k&127;          v = CA*(W0[(size_t)(u*128+vv)*64+h] + W0[(size_t)(vv*128+u)*64+h]); }
      else if (k < 20480) { int l=k-16384; int u=l>>6, vv=l&63; v = C1*(W1[(size_t)(u*64+vv)*64+h] + W1[(size_t)(vv*64+u)*64+h]); }
      else                { int l=k-20480; int u=l>>5, vv=l&31; v = C2*(W2[(size_t)(u*32+vv)*64+h] + W2[(size_t)(vv*32+u)*64+h]); }
      bbwd[e] = f2b(v);
    }
  }
  if (e < 4096) {
    int i = e>>6, j = e&63;
    w1t[j*64+i] = w1[e]; w2t[j*64+i] = w2[e]; w3t[j*64+i] = w3[e];
  }
}

// ---- cooperative x-tile loader: 64 samples x COLS, f32 global -> bf16 LDS ----
template<int R>
DEVI void load_tile(const float* __restrict__ t, int nb, unsigned short* lx)
{
  const int tid = threadIdx.x;
  const int s = tid >> 2, p = tid & 3;          // row, quarter
  constexpr int CH = RC<R>::COLS/4;             // 32 / 48 / 40
  const float4* src = reinterpret_cast<const float4*>(t + (size_t)(nb+s)*TDIM + RC<R>::OFF + p*CH);
  unsigned short* dst = lx + s*RC<R>::STRIDE + p*CH;
  #pragma unroll
  for (int e4 = 0; e4 < CH/4; ++e4) {
    float4 v = src[e4];
    ushort4 o; o.x = f2b(v.x); o.y = f2b(v.y); o.z = f2b(v.z); o.w = f2b(v.w);
    *reinterpret_cast<ushort4*>(dst + e4*4) = o;
  }
}

// ============================================================================
// K1: forward TP, 64-sample tiles (acc[4][4] = 64 regs).  VERBATIM round-4.
// ============================================================================
template<int R>
DEVI void fwd_region(const unsigned short* lx, const uint4* __restrict__ bf,
                     int slot, int lane, f32x4 (&acc)[4][4])
{
  constexpr int NM = RC<R>::NM;
  const int quad = lane>>4, col = lane&15;
  for (int u = slot; u < RC<R>::ROWS; u += 16) {
    #pragma unroll 1
    for (int c = 0; c < RC<R>::NCH; ++c) {
      const int chunk = RC<R>::CBASE + u*RC<R>::NCH + c;
      uint4 bv[4];
      #pragma unroll
      for (int hf = 0; hf < 4; ++hf) bv[hf] = bf[(size_t)(chunk*4 + hf)*64 + lane];
      #pragma unroll
      for (int mf = 0; mf < 4; ++mf) {
        const unsigned short* rowp = lx + (mf*16+col)*RC<R>::STRIDE;
        float xu[NM];
        #pragma unroll
        for (int m = 0; m < NM; ++m) xu[m] = b2f(rowp[u*NM + m]);
        uint4 xq[NM];
        const uint4* xp4 = reinterpret_cast<const uint4*>(rowp + (c*32 + quad*8)*NM);
        #pragma unroll
        for (int q = 0; q < NM; ++q) xq[q] = xp4[q];
        unsigned aw[4];
        #pragma unroll
        for (int jp = 0; jp < 4; ++jp) {
          float p0 = 0.f, p1 = 0.f;
          #pragma unroll
          for (int m = 0; m < NM; ++m) {
            p0 += xu[m] * x4_at(xq, (2*jp+0)*NM + m);
            p1 += xu[m] * x4_at(xq, (2*jp+1)*NM + m);
          }
          aw[jp] = (unsigned)f2b(p0) | ((unsigned)f2b(p1) << 16);
        }
        uint4 afq; afq.x = aw[0]; afq.y = aw[1]; afq.z = aw[2]; afq.w = aw[3];
        #pragma unroll
        for (int hf = 0; hf < 4; ++hf)
          acc[mf][hf] = mfma16(as_bf(afq), as_bf(bv[hf]), acc[mf][hf]);
      }
    }
  }
}

__global__ __launch_bounds__(256,2) void k_fwd(const float* __restrict__ t,
                                               const uint4* __restrict__ bfwd,
                                               float* __restrict__ hpre)
{
  __shared__ __align__(16) unsigned char smem[25600];  // max x-tile (r1); red[16KB] aliases
  unsigned short* lx = (unsigned short*)smem;
  const int nb = blockIdx.x*64;
  const int wv = threadIdx.x>>6, lane = threadIdx.x&63;
  const int slot = blockIdx.y*4 + wv;
  const int quad = lane>>4, col = lane&15;

  f32x4 acc[4][4];
  #pragma unroll
  for (int a = 0; a < 4; ++a)
    #pragma unroll
    for (int b = 0; b < 4; ++b) acc[a][b] = (f32x4){0.f,0.f,0.f,0.f};

  load_tile<0>(t, nb, lx); __syncthreads();
  fwd_region<0>(lx, bfwd, slot, lane, acc); __syncthreads();
  load_tile<1>(t, nb, lx); __syncthreads();
  fwd_region<1>(lx, bfwd, slot, lane, acc); __syncthreads();
  load_tile<2>(t, nb, lx); __syncthreads();
  fwd_region<2>(lx, bfwd, slot, lane, acc); __syncthreads();

  float* red = (float*)smem;                 // 64x64 f32 = 16 KB
  for (int tw = 0; tw < 4; ++tw) {
    if (wv == tw) {
      #pragma unroll
      for (int mf = 0; mf < 4; ++mf)
        #pragma unroll
        for (int hf = 0; hf < 4; ++hf)
          #pragma unroll
          for (int rr = 0; rr < 4; ++rr) {
            int idx = (mf*16 + quad*4 + rr)*64 + hf*16 + col;
            if (tw == 0) red[idx] = acc[mf][hf][rr]; else red[idx] += acc[mf][hf][rr];
          }
    }
    __syncthreads();
  }
  float* hp = hpre + (size_t)blockIdx.y*NSAMP*64;
  for (int i = threadIdx.x; i < 4096; i += 256)
    hp[(size_t)(nb + (i>>6))*64 + (i&63)] = red[i];
}

// ============================================================================
// K2: MLP fwd + bwd (sums 4 ksplit hpre slices on load).  VERBATIM round-4.
// ============================================================================
__global__ __launch_bounds__(256) void k_mlp(
    const float* __restrict__ hpre,
    const float* __restrict__ w1, const float* __restrict__ b1,
    const float* __restrict__ w2, const float* __restrict__ b2,
    const float* __restrict__ w3, const float* __restrict__ b3,
    const float* __restrict__ w1t, const float* __restrict__ w2t, const float* __restrict__ w3t,
    float* __restrict__ xout, unsigned short* __restrict__ dhb)
{
  __shared__ float Bh1[64*64];
  __shared__ float Bh2[64*64];
  __shared__ float Bg2[64*64];
  __shared__ unsigned short Bsp1[64*64];
  const int n  = threadIdx.x & 63;
  const int wv = threadIdx.x >> 6;
  const int jb = __builtin_amdgcn_readfirstlane(wv*16);
  const int nb = blockIdx.x*64;
  const size_t row = (size_t)(nb + n)*64;

  float h[64];
  #pragma unroll
  for (int i = 0; i < 64; ++i)
    h[i] = hpre[row + i] + hpre[(size_t)NSAMP*64 + row + i]
         + hpre[(size_t)2*NSAMP*64 + row + i] + hpre[(size_t)3*NSAMP*64 + row + i];

  float dh2r[16];
  #pragma unroll
  for (int jj = 0; jj < 16; ++jj) {
    int j = jb + jj; float s = 0.f;
    #pragma unroll
    for (int z = 0; z < 64; ++z) s += w3[j*64+z];
    dh2r[jj] = s;
  }
  #pragma unroll
  for (int jj = 0; jj < 16; ++jj) {
    int j = jb + jj; float a = b1[j];
    #pragma unroll
    for (int i = 0; i < 64; ++i) a += h[i]*w1t[j*64+i];
    float sg = 1.f/(1.f + __expf(-a));
    Bh1[j*64+n] = a*sg;
    Bsp1[j*64+n] = f2b(sg*(1.f + a*(1.f-sg)));
  }
  __syncthreads();
  float h1[64];
  #pragma unroll
  for (int i = 0; i < 64; ++i) h1[i] = Bh1[i*64+n];
  #pragma unroll
  for (int jj = 0; jj < 16; ++jj) {
    int j = jb + jj; float a = b2[j];
    #pragma unroll
    for (int i = 0; i < 64; ++i) a += h1[i]*w2t[j*64+i];
    float sg = 1.f/(1.f + __expf(-a));
    Bh2[j*64+n] = a*sg;
    Bg2[j*64+n] = dh2r[jj]*(sg*(1.f + a*(1.f-sg)));
  }
  __syncthreads();
  float h2[64];
  #pragma unroll
  for (int i = 0; i < 64; ++i) h2[i] = Bh2[i*64+n];
  #pragma unroll
  for (int jj = 0; jj < 16; ++jj) {
    int j = jb + jj; float a = b3[j];
    #pragma unroll
    for (int i = 0; i < 64; ++i) a += h2[i]*w3t[j*64+i];
    xout[row + j] = a;
  }
  float g2[64];
  #pragma unroll
  for (int i = 0; i < 64; ++i) g2[i] = Bg2[i*64+n];
  #pragma unroll
  for (int jj = 0; jj < 16; ++jj) {
    int i = jb + jj; float a = 0.f;
    #pragma unroll
    for (int z = 0; z < 64; ++z) a += g2[z]*w2[i*64+z];
    Bh1[i*64+n] = a * b2f(Bsp1[i*64+n]);
  }
  __syncthreads();
  float g1[64];
  #pragma unroll
  for (int i = 0; i < 64; ++i) g1[i] = Bh1[i*64+n];
  #pragma unroll
  for (int jj = 0; jj < 16; ++jj) {
    int i = jb + jj; float a = 0.f;
    #pragma unroll
    for (int z = 0; z < 64; ++z) a += g1[z]*w1[i*64+z];
    dhb[row + i] = f2b(a);
  }
}

// ============================================================================
// K3: backward TP = round-4 EXCEPT dh B-frags in registers (bq[4][2], 32
// VGPRs) instead of the LDS staging buffer.  Single-variable bisection vs
// round-5's triple change.
// ============================================================================
template<int R>
DEVI void bwd_region(const unsigned short* lx, const uint4 (&bq)[4][2],
                     const uint4* __restrict__ ba, int slot, int lane,
                     float* __restrict__ gws, int nb)
{
  constexpr int NM = RC<R>::NM;
  const int quad = lane>>4, col = lane&15;
  for (int u = slot; u < RC<R>::ROWS; u += 16) {
    float gacc[4][NM];
    #pragma unroll
    for (int nf = 0; nf < 4; ++nf)
      #pragma unroll
      for (int m = 0; m < NM; ++m) gacc[nf][m] = 0.f;

    #pragma unroll 1
    for (int c = 0; c < RC<R>::NCH; ++c) {
      uint4 aq[2][2];
      #pragma unroll
      for (int kf = 0; kf < 2; ++kf)
        #pragma unroll
        for (int kc = 0; kc < 2; ++kc) {
          int kb = RC<R>::KBASE + u*(2*RC<R>::NCH) + c*2 + kf;
          aq[kf][kc] = ba[(size_t)(kb*2+kc)*64 + lane];
        }
      #pragma unroll
      for (int kf = 0; kf < 2; ++kf) {
        const int v0 = c*32 + kf*16 + quad*4;
        #pragma unroll
        for (int nf = 0; nf < 4; ++nf) {
          f32x4 a4 = (f32x4){0.f,0.f,0.f,0.f};
          a4 = mfma16(as_bf(aq[kf][0]), as_bf(bq[nf][0]), a4);
          a4 = mfma16(as_bf(aq[kf][1]), as_bf(bq[nf][1]), a4);
          const unsigned short* xp = lx + (nf*16+col)*RC<R>::STRIDE + v0*NM;
          uint2 xq[NM];
          const uint2* xp2 = reinterpret_cast<const uint2*>(xp);
          #pragma unroll
          for (int q = 0; q < NM; ++q) xq[q] = xp2[q];
          #pragma unroll
          for (int rr = 0; rr < 4; ++rr)
            #pragma unroll
            for (int m = 0; m < NM; ++m)
              gacc[nf][m] += a4[rr] * x2_at(xq, rr*NM + m);
        }
      }
    }
    #pragma unroll
    for (int nf = 0; nf < 4; ++nf)
      #pragma unroll
      for (int m = 0; m < NM; ++m) {
        float v = gacc[nf][m];
        v += __shfl_down(v, 32, 64);
        v += __shfl_down(v, 16, 64);
        if (lane < 16)
          gws[(size_t)(RC<R>::OUT + u*NM + m)*NSAMP + nb + nf*16 + lane] = v;
      }
  }
}

__global__ __launch_bounds__(256,2) void k_bwd(const float* __restrict__ t,
                                               const uint4* __restrict__ bbwd,
                                               const unsigned short* __restrict__ dh,
                                               float* __restrict__ gws)
{
  __shared__ __align__(16) unsigned char smem[25600];  // bf16 x-tile only
  unsigned short* lx = (unsigned short*)smem;
  const int nb = blockIdx.x*64;
  const int wv = threadIdx.x>>6, lane = threadIdx.x&63;
  const int slot = blockIdx.y*4 + wv;
  const int cl = lane&15, qd = lane>>4;

  uint4 bq[4][2];   // resident dh B-frags: B[h][n]
  #pragma unroll
  for (int nf = 0; nf < 4; ++nf)
    #pragma unroll
    for (int kc = 0; kc < 2; ++kc)
      bq[nf][kc] = *reinterpret_cast<const uint4*>(dh + (size_t)(nb + nf*16 + cl)*64 + kc*32 + qd*8);

  load_tile<0>(t, nb, lx); __syncthreads();
  bwd_region<0>(lx, bq, bbwd, slot, lane, gws, nb); __syncthreads();
  load_tile<1>(t, nb, lx); __syncthreads();
  bwd_region<1>(lx, bq, bbwd, slot, lane, gws, nb); __syncthreads();
  load_tile<2>(t, nb, lx); __syncthreads();
  bwd_region<2>(lx, bq, bbwd, slot, lane, gws, nb);
}

// ============================================================================
// K4: transpose gws[480][16384] -> y[16384][480], coalesced both sides.
// ============================================================================
__global__ __launch_bounds__(256) void k_tr(const float* __restrict__ gws,
                                            float* __restrict__ y)
{
  __shared__ float tile[32][481];
  const int n0 = blockIdx.x*32;
  for (int idx = threadIdx.x; idx < 480*8; idx += 256) {
    int c = idx >> 3, i4 = idx & 7;
    float4 v = reinterpret_cast<const float4*>(gws + (size_t)c*NSAMP + n0)[i4];
    tile[i4*4+0][c] = v.x; tile[i4*4+1][c] = v.y;
    tile[i4*4+2][c] = v.z; tile[i4*4+3][c] = v.w;
  }
  __syncthreads();
  for (int idx = threadIdx.x; idx < 32*120; idx += 256) {
    int s = idx/120, c4 = idx%120;
    float4 v = { tile[s][c4*4+0], tile[s][c4*4+1], tile[s][c4*4+2], tile[s][c4*4+3] };
    reinterpret_cast<float4*>(y + (size_t)(n0+s)*TDIM)[c4] = v;
  }
}

// ============================================================================
extern "C" void kernel_launch(void* const* d_in, const int* in_sizes, int n_in,
                              void* d_out, int out_size, void* d_ws, size_t ws_size,
                              hipStream_t stream) {
  (void)in_sizes; (void)n_in; (void)out_size; (void)ws_size;
  const float* t  = (const float*)d_in[0];
  const float* W0 = (const float*)d_in[1];
  const float* W1 = (const float*)d_in[2];
  const float* W2 = (const float*)d_in[3];
  const float* w1 = (const float*)d_in[4];
  const float* b1 = (const float*)d_in[5];
  const float* w2 = (const float*)d_in[6];
  const float* b2 = (const float*)d_in[7];
  const float* w3 = (const float*)d_in[8];
  const float* b3 = (const float*)d_in[9];

  char* ws = (char*)d_ws;
  float*          gws  = (float*)(ws + O_GWS);
  unsigned short* bfwd = (unsigned short*)(ws + O_BFWD);
  unsigned short* bbwd = (unsigned short*)(ws + O_BBWD);
  float*          hpre = (float*)(ws + O_HPRE);
  unsigned short* dhb  = (unsigned short*)(ws + O_DH);
  float*          w1t  = (float*)(ws + O_W1T);
  float*          w2t  = (float*)(ws + O_W2T);
  float*          w3t  = (float*)(ws + O_W3T);

  float* xout = (float*)d_out;
  float* y    = (float*)d_out + (size_t)NSAMP*64;

  k_prep<<<dim3(5376), dim3(256), 0, stream>>>(W0, W1, W2, w1, w2, w3,
                                               bfwd, bbwd, w1t, w2t, w3t);
  k_fwd <<<dim3(256,4), dim3(256), 0, stream>>>(t, (const uint4*)bfwd, hpre);
  k_mlp <<<dim3(256), dim3(256), 0, stream>>>(hpre, w1, b1, w2, b2, w3, b3,
                                              w1t, w2t, w3t, xout, dhb);
  k_bwd <<<dim3(256,4), dim3(256), 0, stream>>>(t, (const uint4*)bbwd, dhb, gws);
  k_tr  <<<dim3(512),   dim3(256), 0, stream>>>(gws, y);
}

// Round 7
// 384.216 us; speedup vs baseline: 6.0782x; 1.0251x over previous
//
#include <hip/hip_runtime.h>
#include <hip/hip_bf16.h>
#include <hip/hip_fp16.h>

typedef short    bf16x8 __attribute__((ext_vector_type(8)));
typedef _Float16 f16x8  __attribute__((ext_vector_type(8)));
typedef float    f32x4  __attribute__((ext_vector_type(4)));

#define DEVI __device__ __forceinline__

static constexpr int    NSAMP = 16384;
static constexpr int    TDIM  = 480;
static constexpr int    KTOT  = 21504;

// ---- workspace layout (bytes) ----
static constexpr size_t SZ_B   = (size_t)KTOT * 64 * 2;            // 2,752,512
static constexpr size_t O_GWS  = 0;                                // 31,457,280
static constexpr size_t O_BFWD = 0;                                // aliases gws (dead before k_bwd)
static constexpr size_t O_HPRE = O_BFWD + SZ_B;                    // f32 [4][N][64], aliases gws
static constexpr size_t O_BBWD = (size_t)TDIM * NSAMP * 4;         // after gws
static constexpr size_t O_DH   = O_BBWD + SZ_B;                    // bf16 N*64
static constexpr size_t O_W1T  = O_DH   + (size_t)NSAMP*64*2;
static constexpr size_t O_W2T  = O_W1T + (size_t)64*64*4;
static constexpr size_t O_W3T  = O_W2T + (size_t)64*64*4;

DEVI float b2f(unsigned short s) { union { unsigned u; float f; } v; v.u = (unsigned)s << 16; return v.f; }
DEVI unsigned short f2b(float f) { union { __hip_bfloat16 h; unsigned short s; } v; v.h = __float2bfloat16(f); return v.s; }
DEVI unsigned short f2h(float f) { union { __half h; unsigned short s; } v; v.h = __float2half(f); return v.s; }
DEVI bf16x8 as_bf(uint4 q) { union { uint4 q; bf16x8 v; } u; u.q = q; return u.v; }
DEVI f16x8  as_f16(uint4 q) { union { uint4 q; f16x8 v; } u; u.q = q; return u.v; }
DEVI f32x4 mfma16(bf16x8 a, bf16x8 b, f32x4 c) { return __builtin_amdgcn_mfma_f32_16x16x32_bf16(a, b, c, 0, 0, 0); }
DEVI f32x4 mfma16h(f16x8 a, f16x8 b, f32x4 c)  { return __builtin_amdgcn_mfma_f32_16x16x32_f16 (a, b, c, 0, 0, 0); }
// packed fp16 multiply on raw dwords -> v_pk_mul_f16
DEVI unsigned pkmul(unsigned a, unsigned b) {
  union { unsigned u; __half2 h; } x, y, r;
  x.u = a; y.u = b; r.h = __hmul2(x.h, y.h); return r.u;
}

// pure-SSA bf16 element extraction (no unions -> no alloca risk)
template<int NQ>
DEVI float x4_at(const uint4 (&q)[NQ], int e) {   // e in [0, 8*NQ)
  const uint4 qq = q[e>>3];
  const int wi = (e>>1)&3;
  unsigned w = wi==0?qq.x: wi==1?qq.y: wi==2?qq.z: qq.w;
  return b2f((unsigned short)((e&1)? (w>>16) : w));
}
template<int NQ>
DEVI float x2_at(const uint2 (&q)[NQ], int e) {   // e in [0, 4*NQ)
  const uint2 qq = q[e>>2];
  unsigned w = ((e>>1)&1)? qq.y : qq.x;
  return b2f((unsigned short)((e&1)? (w>>16) : w));
}

template<int R> struct RC;
template<> struct RC<0> { static constexpr int COLS=128, OFF=0,   STRIDE=136, ROWS=128, NCH=4, NM=1, CBASE=0,   KBASE=0,    OUT=0;   };
template<> struct RC<1> { static constexpr int COLS=192, OFF=128, STRIDE=200, ROWS=64,  NCH=2, NM=3, CBASE=512, KBASE=1024, OUT=128; };
template<> struct RC<2> { static constexpr int COLS=160, OFF=320, STRIDE=168, ROWS=32,  NCH=1, NM=5, CBASE=640, KBASE=1280, OUT=320; };

// ============================================================================
// K0: weight prep.  bfwd region-0 chunks (chunk<512) are fp16 (k_fwd uses the
// f16 MFMA there); all other frags bf16.
// ============================================================================
__global__ __launch_bounds__(256) void k_prep(
    const float* __restrict__ W0, const float* __restrict__ W1, const float* __restrict__ W2,
    const float* __restrict__ w1, const float* __restrict__ w2, const float* __restrict__ w3,
    unsigned short* __restrict__ bfwd, unsigned short* __restrict__ bbwd,
    float* __restrict__ w1t, float* __restrict__ w2t, float* __restrict__ w3t)
{
  const int e = blockIdx.x*256 + threadIdx.x;
  const float CA = 0.0068192924f;   // 1/sqrt(21504)
  const float C1 = 0.0039371205f;   // CA/sqrt(3)
  const float C2 = 0.0030496940f;   // CA/sqrt(5)
  if (e < KTOT*64) {
    { // forward B: lane holds B[k=quad*8+j][h=hf*16+col]
      int j = e & 7, lane = (e>>3)&63, hf = (e>>9)&3, chunk = e>>11;
      int k = chunk*32 + (lane>>4)*8 + j;
      int h = hf*16 + (lane&15);
      float v;
      if (k < 16384)      v = CA * W0[(size_t)k*64 + h];
      else if (k < 20480) v = C1 * W1[(size_t)(k-16384)*64 + h];
      else                v = C2 * W2[(size_t)(k-20480)*64 + h];
      bfwd[e] = (chunk < 512) ? f2h(v) : f2b(v);
    }
    { // backward A (symmetrized): lane holds A[k=kb*16+col][h=kc*32+quad*8+j]
      int j = e & 7, lane = (e>>3)&63, kc = (e>>9)&1, kb = e>>10;
      int k = kb*16 + (lane&15);
      int h = kc*32 + (lane>>4)*8 + j;
      float v;
      if (k < 16384)      { int u=k>>7,    vv=k&127;          v = CA*(W0[(size_t)(u*128+vv)*64+h] + W0[(size_t)(vv*128+u)*64+h]); }
      else if (k < 20480) { int l=k-16384; int u=l>>6, vv=l&63; v = C1*(W1[(size_t)(u*64+vv)*64+h] + W1[(size_t)(vv*64+u)*64+h]); }
      else                { int l=k-20480; int u=l>>5, vv=l&31; v = C2*(W2[(size_t)(u*32+vv)*64+h] + W2[(size_t)(vv*32+u)*64+h]); }
      bbwd[e] = f2b(v);
    }
  }
  if (e < 4096) {
    int i = e>>6, j = e&63;
    w1t[j*64+i] = w1[e]; w2t[j*64+i] = w2[e]; w3t[j*64+i] = w3[e];
  }
}

// ---- cooperative x-tile loader: 64 samples x COLS; H=true -> fp16 encode ----
template<int R, bool H>
DEVI void load_tile(const float* __restrict__ t, int nb, unsigned short* lx)
{
  const int tid = threadIdx.x;
  const int s = tid >> 2, p = tid & 3;          // row, quarter
  constexpr int CH = RC<R>::COLS/4;             // 32 / 48 / 40
  const float4* src = reinterpret_cast<const float4*>(t + (size_t)(nb+s)*TDIM + RC<R>::OFF + p*CH);
  unsigned short* dst = lx + s*RC<R>::STRIDE + p*CH;
  #pragma unroll
  for (int e4 = 0; e4 < CH/4; ++e4) {
    float4 v = src[e4];
    ushort4 o;
    if (H) { o.x = f2h(v.x); o.y = f2h(v.y); o.z = f2h(v.z); o.w = f2h(v.w); }
    else   { o.x = f2b(v.x); o.y = f2b(v.y); o.z = f2b(v.z); o.w = f2b(v.w); }
    *reinterpret_cast<ushort4*>(dst + e4*4) = o;
  }
}

// ============================================================================
// K1 region 0: fp16 packed A-build.  A-frag dword j = {xu*x[2j], xu*x[2j+1]}
// via one v_pk_mul_f16 — replaces 8 extracts + 8 muls + 4 cvt-packs.
// ============================================================================
DEVI void fwd_region0_f16(const unsigned short* lx, const uint4* __restrict__ bf,
                          int slot, int lane, f32x4 (&acc)[4][4])
{
  const int quad = lane>>4, col = lane&15;
  for (int u = slot; u < 128; u += 16) {
    unsigned xu2[4];
    #pragma unroll
    for (int mf = 0; mf < 4; ++mf) {
      unsigned s = lx[(mf*16+col)*136 + u];
      xu2[mf] = s | (s<<16);
    }
    #pragma unroll 1
    for (int c = 0; c < 4; ++c) {
      const int chunk = u*4 + c;
      uint4 bv[4];
      #pragma unroll
      for (int hf = 0; hf < 4; ++hf) bv[hf] = bf[(size_t)(chunk*4 + hf)*64 + lane];
      #pragma unroll
      for (int mf = 0; mf < 4; ++mf) {
        const uint4 xq = *reinterpret_cast<const uint4*>(lx + (mf*16+col)*136 + c*32 + quad*8);
        uint4 afq;
        afq.x = pkmul(xu2[mf], xq.x);
        afq.y = pkmul(xu2[mf], xq.y);
        afq.z = pkmul(xu2[mf], xq.z);
        afq.w = pkmul(xu2[mf], xq.w);
        #pragma unroll
        for (int hf = 0; hf < 4; ++hf)
          acc[mf][hf] = mfma16h(as_f16(afq), as_f16(bv[hf]), acc[mf][hf]);
      }
    }
  }
}

// regions 1/2: bf16 path, verbatim round-6
template<int R>
DEVI void fwd_region(const unsigned short* lx, const uint4* __restrict__ bf,
                     int slot, int lane, f32x4 (&acc)[4][4])
{
  constexpr int NM = RC<R>::NM;
  const int quad = lane>>4, col = lane&15;
  for (int u = slot; u < RC<R>::ROWS; u += 16) {
    #pragma unroll 1
    for (int c = 0; c < RC<R>::NCH; ++c) {
      const int chunk = RC<R>::CBASE + u*RC<R>::NCH + c;
      uint4 bv[4];
      #pragma unroll
      for (int hf = 0; hf < 4; ++hf) bv[hf] = bf[(size_t)(chunk*4 + hf)*64 + lane];
      #pragma unroll
      for (int mf = 0; mf < 4; ++mf) {
        const unsigned short* rowp = lx + (mf*16+col)*RC<R>::STRIDE;
        float xu[NM];
        #pragma unroll
        for (int m = 0; m < NM; ++m) xu[m] = b2f(rowp[u*NM + m]);
        uint4 xq[NM];
        const uint4* xp4 = reinterpret_cast<const uint4*>(rowp + (c*32 + quad*8)*NM);
        #pragma unroll
        for (int q = 0; q < NM; ++q) xq[q] = xp4[q];
        unsigned aw[4];
        #pragma unroll
        for (int jp = 0; jp < 4; ++jp) {
          float p0 = 0.f, p1 = 0.f;
          #pragma unroll
          for (int m = 0; m < NM; ++m) {
            p0 += xu[m] * x4_at(xq, (2*jp+0)*NM + m);
            p1 += xu[m] * x4_at(xq, (2*jp+1)*NM + m);
          }
          aw[jp] = (unsigned)f2b(p0) | ((unsigned)f2b(p1) << 16);
        }
        uint4 afq; afq.x = aw[0]; afq.y = aw[1]; afq.z = aw[2]; afq.w = aw[3];
        #pragma unroll
        for (int hf = 0; hf < 4; ++hf)
          acc[mf][hf] = mfma16(as_bf(afq), as_bf(bv[hf]), acc[mf][hf]);
      }
    }
  }
}

__global__ __launch_bounds__(256,2) void k_fwd(const float* __restrict__ t,
                                               const uint4* __restrict__ bfwd,
                                               float* __restrict__ hpre)
{
  __shared__ __align__(16) unsigned char smem[25600];  // max x-tile (r1); red[16KB] aliases
  unsigned short* lx = (unsigned short*)smem;
  const int nb = blockIdx.x*64;
  const int wv = threadIdx.x>>6, lane = threadIdx.x&63;
  const int slot = blockIdx.y*4 + wv;
  const int quad = lane>>4, col = lane&15;

  f32x4 acc[4][4];
  #pragma unroll
  for (int a = 0; a < 4; ++a)
    #pragma unroll
    for (int b = 0; b < 4; ++b) acc[a][b] = (f32x4){0.f,0.f,0.f,0.f};

  load_tile<0,true >(t, nb, lx); __syncthreads();
  fwd_region0_f16(lx, bfwd, slot, lane, acc); __syncthreads();
  load_tile<1,false>(t, nb, lx); __syncthreads();
  fwd_region<1>(lx, bfwd, slot, lane, acc); __syncthreads();
  load_tile<2,false>(t, nb, lx); __syncthreads();
  fwd_region<2>(lx, bfwd, slot, lane, acc); __syncthreads();

  float* red = (float*)smem;                 // 64x64 f32 = 16 KB
  for (int tw = 0; tw < 4; ++tw) {
    if (wv == tw) {
      #pragma unroll
      for (int mf = 0; mf < 4; ++mf)
        #pragma unroll
        for (int hf = 0; hf < 4; ++hf)
          #pragma unroll
          for (int rr = 0; rr < 4; ++rr) {
            int idx = (mf*16 + quad*4 + rr)*64 + hf*16 + col;
            if (tw == 0) red[idx] = acc[mf][hf][rr]; else red[idx] += acc[mf][hf][rr];
          }
    }
    __syncthreads();
  }
  float* hp = hpre + (size_t)blockIdx.y*NSAMP*64;
  for (int i = threadIdx.x; i < 4096; i += 256)
    hp[(size_t)(nb + (i>>6))*64 + (i&63)] = red[i];
}

// ============================================================================
// K2: MLP fwd + bwd.  hpre 4-slice sum now staged through LDS with coalesced
// loads (old path: 64 loads/thread at 256B lane stride = 64-line gathers).
// ============================================================================
__global__ __launch_bounds__(256) void k_mlp(
    const float* __restrict__ hpre,
    const float* __restrict__ w1, const float* __restrict__ b1,
    const float* __restrict__ w2, const float* __restrict__ b2,
    const float* __restrict__ w3, const float* __restrict__ b3,
    const float* __restrict__ w1t, const float* __restrict__ w2t, const float* __restrict__ w3t,
    float* __restrict__ xout, unsigned short* __restrict__ dhb)
{
  __shared__ float Hs[64*65];             // padded: row reads conflict-free
  __shared__ float Bh1[64*64];
  __shared__ float Bh2[64*64];
  __shared__ float Bg2[64*64];
  __shared__ unsigned short Bsp1[64*64];
  const int n  = threadIdx.x & 63;
  const int wv = threadIdx.x >> 6;
  const int jb = __builtin_amdgcn_readfirstlane(wv*16);
  const int nb = blockIdx.x*64;
  const size_t row = (size_t)(nb + n)*64;
  const size_t base = (size_t)nb*64;

  for (int idx = threadIdx.x; idx < 4096; idx += 256) {
    float s = hpre[base + idx]
            + hpre[(size_t)NSAMP*64   + base + idx]
            + hpre[(size_t)2*NSAMP*64 + base + idx]
            + hpre[(size_t)3*NSAMP*64 + base + idx];
    Hs[(idx>>6)*65 + (idx&63)] = s;
  }
  __syncthreads();

  float h[64];
  #pragma unroll
  for (int i = 0; i < 64; ++i) h[i] = Hs[n*65 + i];

  float dh2r[16];
  #pragma unroll
  for (int jj = 0; jj < 16; ++jj) {
    int j = jb + jj; float s = 0.f;
    #pragma unroll
    for (int z = 0; z < 64; ++z) s += w3[j*64+z];
    dh2r[jj] = s;
  }
  #pragma unroll
  for (int jj = 0; jj < 16; ++jj) {
    int j = jb + jj; float a = b1[j];
    #pragma unroll
    for (int i = 0; i < 64; ++i) a += h[i]*w1t[j*64+i];
    float sg = 1.f/(1.f + __expf(-a));
    Bh1[j*64+n] = a*sg;
    Bsp1[j*64+n] = f2b(sg*(1.f + a*(1.f-sg)));
  }
  __syncthreads();
  float h1[64];
  #pragma unroll
  for (int i = 0; i < 64; ++i) h1[i] = Bh1[i*64+n];
  #pragma unroll
  for (int jj = 0; jj < 16; ++jj) {
    int j = jb + jj; float a = b2[j];
    #pragma unroll
    for (int i = 0; i < 64; ++i) a += h1[i]*w2t[j*64+i];
    float sg = 1.f/(1.f + __expf(-a));
    Bh2[j*64+n] = a*sg;
    Bg2[j*64+n] = dh2r[jj]*(sg*(1.f + a*(1.f-sg)));
  }
  __syncthreads();
  float h2[64];
  #pragma unroll
  for (int i = 0; i < 64; ++i) h2[i] = Bh2[i*64+n];
  #pragma unroll
  for (int jj = 0; jj < 16; ++jj) {
    int j = jb + jj; float a = b3[j];
    #pragma unroll
    for (int i = 0; i < 64; ++i) a += h2[i]*w3t[j*64+i];
    xout[row + j] = a;
  }
  float g2[64];
  #pragma unroll
  for (int i = 0; i < 64; ++i) g2[i] = Bg2[i*64+n];
  #pragma unroll
  for (int jj = 0; jj < 16; ++jj) {
    int i = jb + jj; float a = 0.f;
    #pragma unroll
    for (int z = 0; z < 64; ++z) a += g2[z]*w2[i*64+z];
    Bh1[i*64+n] = a * b2f(Bsp1[i*64+n]);
  }
  __syncthreads();
  float g1[64];
  #pragma unroll
  for (int i = 0; i < 64; ++i) g1[i] = Bh1[i*64+n];
  #pragma unroll
  for (int jj = 0; jj < 16; ++jj) {
    int i = jb + jj; float a = 0.f;
    #pragma unroll
    for (int z = 0; z < 64; ++z) a += g1[z]*w1[i*64+z];
    dhb[row + i] = f2b(a);
  }
}

// ============================================================================
// K3: backward TP — VERBATIM round-6 (control; all-bf16).
// ============================================================================
template<int R>
DEVI void bwd_region(const unsigned short* lx, const uint4 (&bq)[4][2],
                     const uint4* __restrict__ ba, int slot, int lane,
                     float* __restrict__ gws, int nb)
{
  constexpr int NM = RC<R>::NM;
  const int quad = lane>>4, col = lane&15;
  for (int u = slot; u < RC<R>::ROWS; u += 16) {
    float gacc[4][NM];
    #pragma unroll
    for (int nf = 0; nf < 4; ++nf)
      #pragma unroll
      for (int m = 0; m < NM; ++m) gacc[nf][m] = 0.f;

    #pragma unroll 1
    for (int c = 0; c < RC<R>::NCH; ++c) {
      uint4 aq[2][2];
      #pragma unroll
      for (int kf = 0; kf < 2; ++kf)
        #pragma unroll
        for (int kc = 0; kc < 2; ++kc) {
          int kb = RC<R>::KBASE + u*(2*RC<R>::NCH) + c*2 + kf;
          aq[kf][kc] = ba[(size_t)(kb*2+kc)*64 + lane];
        }
      #pragma unroll
      for (int kf = 0; kf < 2; ++kf) {
        const int v0 = c*32 + kf*16 + quad*4;
        #pragma unroll
        for (int nf = 0; nf < 4; ++nf) {
          f32x4 a4 = (f32x4){0.f,0.f,0.f,0.f};
          a4 = mfma16(as_bf(aq[kf][0]), as_bf(bq[nf][0]), a4);
          a4 = mfma16(as_bf(aq[kf][1]), as_bf(bq[nf][1]), a4);
          const unsigned short* xp = lx + (nf*16+col)*RC<R>::STRIDE + v0*NM;
          uint2 xq[NM];
          const uint2* xp2 = reinterpret_cast<const uint2*>(xp);
          #pragma unroll
          for (int q = 0; q < NM; ++q) xq[q] = xp2[q];
          #pragma unroll
          for (int rr = 0; rr < 4; ++rr)
            #pragma unroll
            for (int m = 0; m < NM; ++m)
              gacc[nf][m] += a4[rr] * x2_at(xq, rr*NM + m);
        }
      }
    }
    #pragma unroll
    for (int nf = 0; nf < 4; ++nf)
      #pragma unroll
      for (int m = 0; m < NM; ++m) {
        float v = gacc[nf][m];
        v += __shfl_down(v, 32, 64);
        v += __shfl_down(v, 16, 64);
        if (lane < 16)
          gws[(size_t)(RC<R>::OUT + u*NM + m)*NSAMP + nb + nf*16 + lane] = v;
      }
  }
}

__global__ __launch_bounds__(256,2) void k_bwd(const float* __restrict__ t,
                                               const uint4* __restrict__ bbwd,
                                               const unsigned short* __restrict__ dh,
                                               float* __restrict__ gws)
{
  __shared__ __align__(16) unsigned char smem[25600];  // bf16 x-tile only
  unsigned short* lx = (unsigned short*)smem;
  const int nb = blockIdx.x*64;
  const int wv = threadIdx.x>>6, lane = threadIdx.x&63;
  const int slot = blockIdx.y*4 + wv;
  const int cl = lane&15, qd = lane>>4;

  uint4 bq[4][2];   // resident dh B-frags: B[h][n]
  #pragma unroll
  for (int nf = 0; nf < 4; ++nf)
    #pragma unroll
    for (int kc = 0; kc < 2; ++kc)
      bq[nf][kc] = *reinterpret_cast<const uint4*>(dh + (size_t)(nb + nf*16 + cl)*64 + kc*32 + qd*8);

  load_tile<0,false>(t, nb, lx); __syncthreads();
  bwd_region<0>(lx, bq, bbwd, slot, lane, gws, nb); __syncthreads();
  load_tile<1,false>(t, nb, lx); __syncthreads();
  bwd_region<1>(lx, bq, bbwd, slot, lane, gws, nb); __syncthreads();
  load_tile<2,false>(t, nb, lx); __syncthreads();
  bwd_region<2>(lx, bq, bbwd, slot, lane, gws, nb);
}

// ============================================================================
// K4: transpose gws[480][16384] -> y[16384][480], coalesced both sides.
// ============================================================================
__global__ __launch_bounds__(256) void k_tr(const float* __restrict__ gws,
                                            float* __restrict__ y)
{
  __shared__ float tile[32][481];
  const int n0 = blockIdx.x*32;
  for (int idx = threadIdx.x; idx < 480*8; idx += 256) {
    int c = idx >> 3, i4 = idx & 7;
    float4 v = reinterpret_cast<const float4*>(gws + (size_t)c*NSAMP + n0)[i4];
    tile[i4*4+0][c] = v.x; tile[i4*4+1][c] = v.y;
    tile[i4*4+2][c] = v.z; tile[i4*4+3][c] = v.w;
  }
  __syncthreads();
  for (int idx = threadIdx.x; idx < 32*120; idx += 256) {
    int s = idx/120, c4 = idx%120;
    float4 v = { tile[s][c4*4+0], tile[s][c4*4+1], tile[s][c4*4+2], tile[s][c4*4+3] };
    reinterpret_cast<float4*>(y + (size_t)(n0+s)*TDIM)[c4] = v;
  }
}

// ============================================================================
extern "C" void kernel_launch(void* const* d_in, const int* in_sizes, int n_in,
                              void* d_out, int out_size, void* d_ws, size_t ws_size,
                              hipStream_t stream) {
  (void)in_sizes; (void)n_in; (void)out_size; (void)ws_size;
  const float* t  = (const float*)d_in[0];
  const float* W0 = (const float*)d_in[1];
  const float* W1 = (const float*)d_in[2];
  const float* W2 = (const float*)d_in[3];
  const float* w1 = (const float*)d_in[4];
  const float* b1 = (const float*)d_in[5];
  const float* w2 = (const float*)d_in[6];
  const float* b2 = (const float*)d_in[7];
  const float* w3 = (const float*)d_in[8];
  const float* b3 = (const float*)d_in[9];

  char* ws = (char*)d_ws;
  float*          gws  = (float*)(ws + O_GWS);
  unsigned short* bfwd = (unsigned short*)(ws + O_BFWD);
  unsigned short* bbwd = (unsigned short*)(ws + O_BBWD);
  float*          hpre = (float*)(ws + O_HPRE);
  unsigned short* dhb  = (unsigned short*)(ws + O_DH);
  float*          w1t  = (float*)(ws + O_W1T);
  float*          w2t  = (float*)(ws + O_W2T);
  float*          w3t  = (float*)(ws + O_W3T);

  float* xout = (float*)d_out;
  float* y    = (float*)d_out + (size_t)NSAMP*64;

  k_prep<<<dim3(5376), dim3(256), 0, stream>>>(W0, W1, W2, w1, w2, w3,
                                               bfwd, bbwd, w1t, w2t, w3t);
  k_fwd <<<dim3(256,4), dim3(256), 0, stream>>>(t, (const uint4*)bfwd, hpre);
  k_mlp <<<dim3(256), dim3(256), 0, stream>>>(hpre, w1, b1, w2, b2, w3, b3,
                                              w1t, w2t, w3t, xout, dhb);
  k_bwd <<<dim3(256,4), dim3(256), 0, stream>>>(t, (const uint4*)bbwd, dhb, gws);
  k_tr  <<<dim3(512),   dim3(256), 0, stream>>>(gws, y);
}